// Round 1
// baseline (2934.464 us; speedup 1.0000x reference)
//
#include <hip/hip_runtime.h>

static constexpr float BN_EPS = 1e-5f;

// Detect whether edge_index is int64 (all high words of values < 2^31 are 0)
// or int32 (random indices -> essentially impossible that 256 sampled odd
// words are all zero).
__global__ __launch_bounds__(256) void k_detect_i64(const unsigned* __restrict__ ei,
                                                    int* __restrict__ flag) {
    if (blockIdx.x == 0 && threadIdx.x == 0) {
        int allz = 1;
        for (int i = 0; i < 256; ++i) {
            if (ei[2 * i + 1] != 0u) { allz = 0; break; }
        }
        *flag = allz;
    }
}

__global__ __launch_bounds__(256) void k_init_deg(int* __restrict__ deg, int n) {
    int i = blockIdx.x * 256 + threadIdx.x;
    if (i < n) deg[i] = 1;  // self loop
}

__global__ __launch_bounds__(256) void k_count_deg(const void* __restrict__ eidx, int E,
                                                   const int* __restrict__ flag,
                                                   int* __restrict__ deg) {
    int e = blockIdx.x * 256 + threadIdx.x;
    if (e >= E) return;
    int d;
    if (*flag) d = (int)((const long long*)eidx)[E + e];
    else       d = ((const int*)eidx)[E + e];
    atomicAdd(&deg[d], 1);
}

__global__ __launch_bounds__(256) void k_dinv(const int* __restrict__ deg,
                                              float* __restrict__ dinv, int n) {
    int i = blockIdx.x * 256 + threadIdx.x;
    if (i < n) dinv[i] = rsqrtf((float)deg[i]);
}

// Y[n,128] = X[n,128] @ W[128,128], f32, W + X tile staged in LDS.
__global__ __launch_bounds__(256) void k_gemm(const float* __restrict__ X,
                                              const float* __restrict__ W,
                                              float* __restrict__ Y, int n) {
    __shared__ float Ws[128 * 128];  // 64 KiB
    __shared__ float Xs[64 * 128];   // 32 KiB
    const int tid = threadIdx.x;
    for (int i = tid; i < 128 * 32; i += 256)
        ((float4*)Ws)[i] = ((const float4*)W)[i];
    const int row0 = blockIdx.x * 64;
    for (int i = tid; i < 64 * 32; i += 256) {
        int r = i >> 5, c = i & 31;
        int gr = row0 + r;
        float4 v = (gr < n) ? ((const float4*)X)[(size_t)gr * 32 + c]
                            : float4{0.f, 0.f, 0.f, 0.f};
        ((float4*)Xs)[i] = v;
    }
    __syncthreads();
    const int c4 = (tid & 31) * 4;  // output column start
    const int rb = tid >> 5;        // row base 0..7 (rows rb, rb+8, ..., rb+56)
    float4 acc[8];
#pragma unroll
    for (int j = 0; j < 8; ++j) acc[j] = float4{0.f, 0.f, 0.f, 0.f};
    for (int k = 0; k < 128; ++k) {
        float4 w = *(const float4*)&Ws[k * 128 + c4];
#pragma unroll
        for (int j = 0; j < 8; ++j) {
            float xv = Xs[(rb + 8 * j) * 128 + k];  // half-wave broadcast, conflict-free
            acc[j].x = fmaf(xv, w.x, acc[j].x);
            acc[j].y = fmaf(xv, w.y, acc[j].y);
            acc[j].z = fmaf(xv, w.z, acc[j].z);
            acc[j].w = fmaf(xv, w.w, acc[j].w);
        }
    }
#pragma unroll
    for (int j = 0; j < 8; ++j) {
        int r = row0 + rb + 8 * j;
        if (r < n) *(float4*)&Y[(size_t)r * 128 + c4] = acc[j];
    }
}

// B[i,:] = H[i,:] * dinv[i]^2 + bias   (self-loop contribution + bias; writes all)
__global__ __launch_bounds__(256) void k_selfloop(const float* __restrict__ H,
                                                  const float* __restrict__ dinv,
                                                  const float* __restrict__ bias,
                                                  float* __restrict__ B, int n) {
    int idx = blockIdx.x * 256 + threadIdx.x;
    int total = n * 32;
    if (idx >= total) return;
    int r = idx >> 5, c = idx & 31;
    float s = dinv[r];
    s *= s;
    float4 h = ((const float4*)H)[idx];
    float4 bb = ((const float4*)bias)[c];
    float4 o{fmaf(h.x, s, bb.x), fmaf(h.y, s, bb.y),
             fmaf(h.z, s, bb.z), fmaf(h.w, s, bb.w)};
    ((float4*)B)[idx] = o;
}

// One edge per 32-thread group; gather h[src]*norm, atomic scatter to B[dst].
__global__ __launch_bounds__(256) void k_edge(const void* __restrict__ eidx, int E,
                                              const int* __restrict__ flag,
                                              const float* __restrict__ dinv,
                                              const float* __restrict__ H,
                                              float* __restrict__ B) {
    int e = blockIdx.x * 8 + (threadIdx.x >> 5);
    if (e >= E) return;
    int lane = threadIdx.x & 31;
    int s, d;
    if (*flag) {
        s = (int)((const long long*)eidx)[e];
        d = (int)((const long long*)eidx)[E + e];
    } else {
        s = ((const int*)eidx)[e];
        d = ((const int*)eidx)[E + e];
    }
    float nrm = dinv[s] * dinv[d];
    float4 h = ((const float4*)(H + (size_t)s * 128))[lane];
    float* out = B + (size_t)d * 128 + lane * 4;
    atomicAdd(out + 0, h.x * nrm);
    atomicAdd(out + 1, h.y * nrm);
    atomicAdd(out + 2, h.z * nrm);
    atomicAdd(out + 3, h.w * nrm);
}

// Column sums / sumsq into stats[0:128]=sum, stats[128:256]=sumsq (pre-zeroed).
__global__ __launch_bounds__(256) void k_bnstats(const float* __restrict__ B, int n,
                                                 float* __restrict__ stats) {
    __shared__ float rs[256], rss[256];
    int col = threadIdx.x & 127;
    int rg = threadIdx.x >> 7;  // 0 or 1
    float s = 0.f, ss = 0.f;
    for (int r = blockIdx.x * 2 + rg; r < n; r += gridDim.x * 2) {
        float v = B[(size_t)r * 128 + col];
        s += v;
        ss = fmaf(v, v, ss);
    }
    rs[threadIdx.x] = s;
    rss[threadIdx.x] = ss;
    __syncthreads();
    if (threadIdx.x < 128) {
        atomicAdd(&stats[col], rs[threadIdx.x] + rs[threadIdx.x + 128]);
        atomicAdd(&stats[128 + col], rss[threadIdx.x] + rss[threadIdx.x + 128]);
    }
}

// out = relu((x - mean) * rsqrt(var+eps) * gamma + beta)
__global__ __launch_bounds__(256) void k_bnapply(const float* __restrict__ Bin,
                                                 float* __restrict__ out,
                                                 const float* __restrict__ stats,
                                                 const float* __restrict__ gamma,
                                                 const float* __restrict__ beta,
                                                 int n, float invn) {
    int idx = blockIdx.x * 256 + threadIdx.x;
    int total = n * 32;
    if (idx >= total) return;
    int c4 = (idx & 31) * 4;
    float4 x = ((const float4*)Bin)[idx];
    float4 o;
#pragma unroll
    for (int j = 0; j < 4; ++j) {
        int c = c4 + j;
        float m = stats[c] * invn;
        float var = fmaf(-m, m, stats[128 + c] * invn);
        float sc = rsqrtf(var + BN_EPS) * gamma[c];
        float sh = fmaf(-m, sc, beta[c]);
        float v = fmaf((&x.x)[j], sc, sh);
        (&o.x)[j] = fmaxf(v, 0.f);
    }
    ((float4*)out)[idx] = o;
}

extern "C" void kernel_launch(void* const* d_in, const int* in_sizes, int n_in,
                              void* d_out, int out_size, void* d_ws, size_t ws_size,
                              hipStream_t stream) {
    const float* x   = (const float*)d_in[0];
    const void*  ei  = d_in[1];
    const float* W1  = (const float*)d_in[2];
    const float* b1  = (const float*)d_in[3];
    const float* g1  = (const float*)d_in[4];
    const float* be1 = (const float*)d_in[5];
    const float* W2  = (const float*)d_in[6];
    const float* b2  = (const float*)d_in[7];
    const float* g2  = (const float*)d_in[8];
    const float* be2 = (const float*)d_in[9];

    const int n = in_sizes[0] / 128;
    const int E = in_sizes[1] / 2;
    const float invn = 1.0f / (float)n;

    float* A    = (float*)d_ws;                    // n*128 f32
    float* B    = A + (size_t)n * 128;             // n*128 f32
    int*   deg  = (int*)(B + (size_t)n * 128);     // n int
    float* dinv = (float*)(deg + n);               // n f32
    float* stats = dinv + n;                       // 256 f32
    int*   flag = (int*)(stats + 256);             // 1 int
    float* out  = (float*)d_out;

    const int nb_n   = (n + 255) / 256;
    const int nb_e   = (E + 255) / 256;
    const int nb_el  = (n * 32 + 255) / 256;
    const int nb_gm  = (n + 63) / 64;
    const int nb_edge = (E + 7) / 8;

    k_detect_i64<<<1, 256, 0, stream>>>((const unsigned*)ei, flag);
    k_init_deg<<<nb_n, 256, 0, stream>>>(deg, n);
    k_count_deg<<<nb_e, 256, 0, stream>>>(ei, E, flag, deg);
    k_dinv<<<nb_n, 256, 0, stream>>>(deg, dinv, n);

    // ---- layer 1 ----
    k_gemm<<<nb_gm, 256, 0, stream>>>(x, W1, A, n);
    k_selfloop<<<nb_el, 256, 0, stream>>>(A, dinv, b1, B, n);
    k_edge<<<nb_edge, 256, 0, stream>>>(ei, E, flag, dinv, A, B);
    hipMemsetAsync(stats, 0, 256 * sizeof(float), stream);
    k_bnstats<<<256, 256, 0, stream>>>(B, n, stats);
    k_bnapply<<<nb_el, 256, 0, stream>>>(B, B, stats, g1, be1, n, invn);

    // ---- layer 2 ----
    k_gemm<<<nb_gm, 256, 0, stream>>>(B, W2, A, n);
    k_selfloop<<<nb_el, 256, 0, stream>>>(A, dinv, b2, B, n);
    k_edge<<<nb_edge, 256, 0, stream>>>(ei, E, flag, dinv, A, B);
    hipMemsetAsync(stats, 0, 256 * sizeof(float), stream);
    k_bnstats<<<256, 256, 0, stream>>>(B, n, stats);
    k_bnapply<<<nb_el, 256, 0, stream>>>(B, out, stats, g2, be2, n, invn);
}

// Round 2
// 523.143 us; speedup vs baseline: 5.6093x; 5.6093x over previous
//
#include <hip/hip_runtime.h>

static constexpr float BN_EPS = 1e-5f;

// Detect whether edge_index is int64 (high words all zero) or int32.
__global__ __launch_bounds__(256) void k_detect_i64(const unsigned* __restrict__ ei,
                                                    int* __restrict__ flag) {
    if (blockIdx.x == 0 && threadIdx.x == 0) {
        int allz = 1;
        for (int i = 0; i < 256; ++i) {
            if (ei[2 * i + 1] != 0u) { allz = 0; break; }
        }
        *flag = allz;
    }
}

__global__ __launch_bounds__(256) void k_init_deg(int* __restrict__ deg, int n) {
    int i = blockIdx.x * 256 + threadIdx.x;
    if (i < n) deg[i] = 1;  // self loop
}

__global__ __launch_bounds__(256) void k_count_deg(const void* __restrict__ eidx, int E,
                                                   const int* __restrict__ flag,
                                                   int* __restrict__ deg) {
    int e = blockIdx.x * 256 + threadIdx.x;
    if (e >= E) return;
    int d;
    if (*flag) d = (int)((const long long*)eidx)[E + e];
    else       d = ((const int*)eidx)[E + e];
    atomicAdd(&deg[d], 1);
}

__global__ __launch_bounds__(256) void k_dinv(const int* __restrict__ deg,
                                              float* __restrict__ dinv, int n) {
    int i = blockIdx.x * 256 + threadIdx.x;
    if (i < n) dinv[i] = rsqrtf((float)deg[i]);
}

// Single-block exclusive scan of (deg[i]-1) -> row_ptr[0..n], cursor[i]=row_ptr[i].
__global__ __launch_bounds__(1024) void k_scan(const int* __restrict__ deg, int n,
                                               int* __restrict__ row_ptr,
                                               int* __restrict__ cursor) {
    __shared__ int sdata[1024];
    const int t = threadIdx.x;
    const int chunk = (n + 1023) / 1024;
    const int lo = t * chunk;
    const int hi = min(lo + chunk, n);
    int mysum = 0;
    for (int i = lo; i < hi; ++i) mysum += deg[i] - 1;
    sdata[t] = mysum;
    __syncthreads();
    for (int off = 1; off < 1024; off <<= 1) {
        int v = (t >= off) ? sdata[t - off] : 0;
        __syncthreads();
        sdata[t] += v;
        __syncthreads();
    }
    int run = sdata[t] - mysum;  // exclusive prefix
    for (int i = lo; i < hi; ++i) {
        row_ptr[i] = run;
        cursor[i] = run;
        run += deg[i] - 1;
    }
    if (t == 1023) row_ptr[n] = sdata[1023];
}

// Bin edges by dst: rec[pos] = {src, bits(norm)}.
__global__ __launch_bounds__(256) void k_scatter(const void* __restrict__ eidx, int E,
                                                 const int* __restrict__ flag,
                                                 const float* __restrict__ dinv,
                                                 int* __restrict__ cursor,
                                                 int2* __restrict__ rec) {
    int e = blockIdx.x * 256 + threadIdx.x;
    if (e >= E) return;
    int s, d;
    if (*flag) {
        s = (int)((const long long*)eidx)[e];
        d = (int)((const long long*)eidx)[E + e];
    } else {
        s = ((const int*)eidx)[e];
        d = ((const int*)eidx)[E + e];
    }
    float nrm = dinv[s] * dinv[d];
    int pos = atomicAdd(&cursor[d], 1);
    rec[pos] = make_int2(s, __float_as_int(nrm));
}

// Y[n,128] = X[n,128] @ W[128,128], f32, W + X tile staged in LDS.
__global__ __launch_bounds__(256) void k_gemm(const float* __restrict__ X,
                                              const float* __restrict__ W,
                                              float* __restrict__ Y, int n) {
    __shared__ float Ws[128 * 128];
    __shared__ float Xs[64 * 128];
    const int tid = threadIdx.x;
    for (int i = tid; i < 128 * 32; i += 256)
        ((float4*)Ws)[i] = ((const float4*)W)[i];
    const int row0 = blockIdx.x * 64;
    for (int i = tid; i < 64 * 32; i += 256) {
        int r = i >> 5, c = i & 31;
        int gr = row0 + r;
        float4 v = (gr < n) ? ((const float4*)X)[(size_t)gr * 32 + c]
                            : float4{0.f, 0.f, 0.f, 0.f};
        ((float4*)Xs)[i] = v;
    }
    __syncthreads();
    const int c4 = (tid & 31) * 4;
    const int rb = tid >> 5;
    float4 acc[8];
#pragma unroll
    for (int j = 0; j < 8; ++j) acc[j] = float4{0.f, 0.f, 0.f, 0.f};
    for (int k = 0; k < 128; ++k) {
        float4 w = *(const float4*)&Ws[k * 128 + c4];
#pragma unroll
        for (int j = 0; j < 8; ++j) {
            float xv = Xs[(rb + 8 * j) * 128 + k];
            acc[j].x = fmaf(xv, w.x, acc[j].x);
            acc[j].y = fmaf(xv, w.y, acc[j].y);
            acc[j].z = fmaf(xv, w.z, acc[j].z);
            acc[j].w = fmaf(xv, w.w, acc[j].w);
        }
    }
#pragma unroll
    for (int j = 0; j < 8; ++j) {
        int r = row0 + rb + 8 * j;
        if (r < n) *(float4*)&Y[(size_t)r * 128 + c4] = acc[j];
    }
}

// One wave per dst row: B[d] = H[d]*dinv[d]^2 + bias + sum_{e in bucket} H[src_e]*norm_e
__global__ __launch_bounds__(256) void k_agg(const int2* __restrict__ rec,
                                             const int* __restrict__ row_ptr,
                                             const float* __restrict__ H,
                                             const float* __restrict__ dinv,
                                             const float* __restrict__ bias,
                                             float* __restrict__ B, int n) {
    const int d = blockIdx.x * 4 + (threadIdx.x >> 6);
    if (d >= n) return;
    const int lane = threadIdx.x & 63;
    float s = dinv[d];
    s *= s;
    float2 h = ((const float2*)(H + (size_t)d * 128))[lane];
    float2 bb = ((const float2*)bias)[lane];
    float2 acc{fmaf(h.x, s, bb.x), fmaf(h.y, s, bb.y)};
    int e = row_ptr[d];
    const int end = row_ptr[d + 1];
    for (; e + 1 < end; e += 2) {
        int2 r0 = rec[e], r1 = rec[e + 1];
        float2 h0 = ((const float2*)(H + (size_t)r0.x * 128))[lane];
        float2 h1 = ((const float2*)(H + (size_t)r1.x * 128))[lane];
        float n0 = __int_as_float(r0.y), n1 = __int_as_float(r1.y);
        acc.x = fmaf(h0.x, n0, acc.x);
        acc.y = fmaf(h0.y, n0, acc.y);
        acc.x = fmaf(h1.x, n1, acc.x);
        acc.y = fmaf(h1.y, n1, acc.y);
    }
    if (e < end) {
        int2 r0 = rec[e];
        float2 h0 = ((const float2*)(H + (size_t)r0.x * 128))[lane];
        float n0 = __int_as_float(r0.y);
        acc.x = fmaf(h0.x, n0, acc.x);
        acc.y = fmaf(h0.y, n0, acc.y);
    }
    ((float2*)(B + (size_t)d * 128))[lane] = acc;
}

// ---- fallback (atomic) path kernels ----
__global__ __launch_bounds__(256) void k_selfloop(const float* __restrict__ H,
                                                  const float* __restrict__ dinv,
                                                  const float* __restrict__ bias,
                                                  float* __restrict__ B, int n) {
    int idx = blockIdx.x * 256 + threadIdx.x;
    int total = n * 32;
    if (idx >= total) return;
    int r = idx >> 5, c = idx & 31;
    float s = dinv[r];
    s *= s;
    float4 h = ((const float4*)H)[idx];
    float4 bb = ((const float4*)bias)[c];
    float4 o{fmaf(h.x, s, bb.x), fmaf(h.y, s, bb.y),
             fmaf(h.z, s, bb.z), fmaf(h.w, s, bb.w)};
    ((float4*)B)[idx] = o;
}

__global__ __launch_bounds__(256) void k_edge(const void* __restrict__ eidx, int E,
                                              const int* __restrict__ flag,
                                              const float* __restrict__ dinv,
                                              const float* __restrict__ H,
                                              float* __restrict__ B) {
    int e = blockIdx.x * 8 + (threadIdx.x >> 5);
    if (e >= E) return;
    int lane = threadIdx.x & 31;
    int s, d;
    if (*flag) {
        s = (int)((const long long*)eidx)[e];
        d = (int)((const long long*)eidx)[E + e];
    } else {
        s = ((const int*)eidx)[e];
        d = ((const int*)eidx)[E + e];
    }
    float nrm = dinv[s] * dinv[d];
    float4 h = ((const float4*)(H + (size_t)s * 128))[lane];
    float* out = B + (size_t)d * 128 + lane * 4;
    atomicAdd(out + 0, h.x * nrm);
    atomicAdd(out + 1, h.y * nrm);
    atomicAdd(out + 2, h.z * nrm);
    atomicAdd(out + 3, h.w * nrm);
}

// Column sums / sumsq into stats[0:128]=sum, stats[128:256]=sumsq (pre-zeroed).
__global__ __launch_bounds__(256) void k_bnstats(const float* __restrict__ B, int n,
                                                 float* __restrict__ stats) {
    __shared__ float rs[256], rss[256];
    int col = threadIdx.x & 127;
    int rg = threadIdx.x >> 7;
    float s = 0.f, ss = 0.f;
    for (int r = blockIdx.x * 2 + rg; r < n; r += gridDim.x * 2) {
        float v = B[(size_t)r * 128 + col];
        s += v;
        ss = fmaf(v, v, ss);
    }
    rs[threadIdx.x] = s;
    rss[threadIdx.x] = ss;
    __syncthreads();
    if (threadIdx.x < 128) {
        atomicAdd(&stats[col], rs[threadIdx.x] + rs[threadIdx.x + 128]);
        atomicAdd(&stats[128 + col], rss[threadIdx.x] + rss[threadIdx.x + 128]);
    }
}

__global__ __launch_bounds__(256) void k_bnapply(const float* __restrict__ Bin,
                                                 float* __restrict__ out,
                                                 const float* __restrict__ stats,
                                                 const float* __restrict__ gamma,
                                                 const float* __restrict__ beta,
                                                 int n, float invn) {
    int idx = blockIdx.x * 256 + threadIdx.x;
    int total = n * 32;
    if (idx >= total) return;
    int c4 = (idx & 31) * 4;
    float4 x = ((const float4*)Bin)[idx];
    float4 o;
#pragma unroll
    for (int j = 0; j < 4; ++j) {
        int c = c4 + j;
        float m = stats[c] * invn;
        float var = fmaf(-m, m, stats[128 + c] * invn);
        float sc = rsqrtf(var + BN_EPS) * gamma[c];
        float sh = fmaf(-m, sc, beta[c]);
        float v = fmaf((&x.x)[j], sc, sh);
        (&o.x)[j] = fmaxf(v, 0.f);
    }
    ((float4*)out)[idx] = o;
}

extern "C" void kernel_launch(void* const* d_in, const int* in_sizes, int n_in,
                              void* d_out, int out_size, void* d_ws, size_t ws_size,
                              hipStream_t stream) {
    const float* x   = (const float*)d_in[0];
    const void*  ei  = d_in[1];
    const float* W1  = (const float*)d_in[2];
    const float* b1  = (const float*)d_in[3];
    const float* g1  = (const float*)d_in[4];
    const float* be1 = (const float*)d_in[5];
    const float* W2  = (const float*)d_in[6];
    const float* b2  = (const float*)d_in[7];
    const float* g2  = (const float*)d_in[8];
    const float* be2 = (const float*)d_in[9];

    const int n = in_sizes[0] / 128;
    const int E = in_sizes[1] / 2;
    const float invn = 1.0f / (float)n;

    char* p = (char*)d_ws;
    float* A = (float*)p;            p += (size_t)n * 128 * 4;
    float* B = (float*)p;            p += (size_t)n * 128 * 4;
    int2*  rec = (int2*)p;           p += (size_t)E * 8;
    int*   row_ptr = (int*)p;        p += (size_t)(n + 1) * 4;
    int*   cursor = (int*)p;         p += (size_t)n * 4;
    int*   deg = (int*)p;            p += (size_t)n * 4;
    float* dinv = (float*)p;         p += (size_t)n * 4;
    float* stats = (float*)p;        p += 256 * 4;
    int*   flag = (int*)p;           p += 16;
    const size_t needed = (size_t)(p - (char*)d_ws);
    const bool csr_ok = needed <= ws_size;
    float* out = (float*)d_out;

    const int nb_n    = (n + 255) / 256;
    const int nb_e    = (E + 255) / 256;
    const int nb_el   = (n * 32 + 255) / 256;
    const int nb_gm   = (n + 63) / 64;
    const int nb_edge = (E + 7) / 8;
    const int nb_agg  = (n + 3) / 4;

    k_detect_i64<<<1, 256, 0, stream>>>((const unsigned*)ei, flag);
    k_init_deg<<<nb_n, 256, 0, stream>>>(deg, n);
    k_count_deg<<<nb_e, 256, 0, stream>>>(ei, E, flag, deg);
    k_dinv<<<nb_n, 256, 0, stream>>>(deg, dinv, n);

    if (csr_ok) {
        k_scan<<<1, 1024, 0, stream>>>(deg, n, row_ptr, cursor);
        k_scatter<<<nb_e, 256, 0, stream>>>(ei, E, flag, dinv, cursor, rec);

        // ---- layer 1 ----
        k_gemm<<<nb_gm, 256, 0, stream>>>(x, W1, A, n);
        k_agg<<<nb_agg, 256, 0, stream>>>(rec, row_ptr, A, dinv, b1, B, n);
        hipMemsetAsync(stats, 0, 256 * sizeof(float), stream);
        k_bnstats<<<256, 256, 0, stream>>>(B, n, stats);
        k_bnapply<<<nb_el, 256, 0, stream>>>(B, B, stats, g1, be1, n, invn);

        // ---- layer 2 ----
        k_gemm<<<nb_gm, 256, 0, stream>>>(B, W2, A, n);
        k_agg<<<nb_agg, 256, 0, stream>>>(rec, row_ptr, A, dinv, b2, B, n);
        hipMemsetAsync(stats, 0, 256 * sizeof(float), stream);
        k_bnstats<<<256, 256, 0, stream>>>(B, n, stats);
        k_bnapply<<<nb_el, 256, 0, stream>>>(B, out, stats, g2, be2, n, invn);
    } else {
        // fallback: atomic scatter path (R0)
        k_gemm<<<nb_gm, 256, 0, stream>>>(x, W1, A, n);
        k_selfloop<<<nb_el, 256, 0, stream>>>(A, dinv, b1, B, n);
        k_edge<<<nb_edge, 256, 0, stream>>>(ei, E, flag, dinv, A, B);
        hipMemsetAsync(stats, 0, 256 * sizeof(float), stream);
        k_bnstats<<<256, 256, 0, stream>>>(B, n, stats);
        k_bnapply<<<nb_el, 256, 0, stream>>>(B, B, stats, g1, be1, n, invn);

        k_gemm<<<nb_gm, 256, 0, stream>>>(B, W2, A, n);
        k_selfloop<<<nb_el, 256, 0, stream>>>(A, dinv, b2, B, n);
        k_edge<<<nb_edge, 256, 0, stream>>>(ei, E, flag, dinv, A, B);
        hipMemsetAsync(stats, 0, 256 * sizeof(float), stream);
        k_bnstats<<<256, 256, 0, stream>>>(B, n, stats);
        k_bnapply<<<nb_el, 256, 0, stream>>>(B, out, stats, g2, be2, n, invn);
    }
}

// Round 3
// 431.310 us; speedup vs baseline: 6.8036x; 1.2129x over previous
//
#include <hip/hip_runtime.h>

static constexpr float BN_EPS = 1e-5f;

#define SCAN_PER 8
#define SCAN_TILE 2048  // 256 threads * 8

// Detect whether edge_index is int64 (high words all zero) or int32.
__global__ __launch_bounds__(256) void k_detect_i64(const unsigned* __restrict__ ei,
                                                    int* __restrict__ flag) {
    if (blockIdx.x == 0 && threadIdx.x == 0) {
        int allz = 1;
        for (int i = 0; i < 256; ++i) {
            if (ei[2 * i + 1] != 0u) { allz = 0; break; }
        }
        *flag = allz;
    }
}

__global__ __launch_bounds__(256) void k_init_deg(int* __restrict__ deg, int n) {
    int i = blockIdx.x * 256 + threadIdx.x;
    if (i < n) deg[i] = 1;  // self loop
}

__global__ __launch_bounds__(256) void k_count_deg(const void* __restrict__ eidx, int E,
                                                   const int* __restrict__ flag,
                                                   int* __restrict__ deg) {
    int e = blockIdx.x * 256 + threadIdx.x;
    if (e >= E) return;
    int d;
    if (*flag) d = (int)((const long long*)eidx)[E + e];
    else       d = ((const int*)eidx)[E + e];
    atomicAdd(&deg[d], 1);
}

__global__ __launch_bounds__(256) void k_dinv(const int* __restrict__ deg,
                                              float* __restrict__ dinv, int n) {
    int i = blockIdx.x * 256 + threadIdx.x;
    if (i < n) dinv[i] = rsqrtf((float)deg[i]);
}

// ---- two-level parallel exclusive scan of (deg[i]-1) ----
__global__ __launch_bounds__(256) void k_scan1(const int* __restrict__ deg, int n,
                                               int* __restrict__ partials) {
    __shared__ int sd[256];
    const int tid = threadIdx.x;
    const int base = blockIdx.x * SCAN_TILE + tid * SCAN_PER;
    int s = 0;
#pragma unroll
    for (int j = 0; j < SCAN_PER; ++j) {
        int i = base + j;
        if (i < n) s += deg[i] - 1;
    }
    sd[tid] = s;
    __syncthreads();
    for (int off = 128; off > 0; off >>= 1) {
        if (tid < off) sd[tid] += sd[tid + off];
        __syncthreads();
    }
    if (tid == 0) partials[blockIdx.x] = sd[0];
}

__global__ __launch_bounds__(64) void k_scan2(int* __restrict__ partials, int nb,
                                              int* __restrict__ total_out) {
    if (threadIdx.x == 0 && blockIdx.x == 0) {
        int run = 0;
        for (int b = 0; b < nb; ++b) {
            int t = partials[b];
            partials[b] = run;
            run += t;
        }
        *total_out = run;  // row_ptr[n]
    }
}

__global__ __launch_bounds__(256) void k_scan3(const int* __restrict__ deg, int n,
                                               const int* __restrict__ partials,
                                               int* __restrict__ row_ptr,
                                               int* __restrict__ cursor) {
    __shared__ int sd[256];
    const int tid = threadIdx.x;
    const int base = blockIdx.x * SCAN_TILE + tid * SCAN_PER;
    int loc[SCAN_PER];
    int s = 0;
#pragma unroll
    for (int j = 0; j < SCAN_PER; ++j) {
        int i = base + j;
        int v = (i < n) ? deg[i] - 1 : 0;
        loc[j] = s;  // exclusive within thread
        s += v;
    }
    sd[tid] = s;
    __syncthreads();
    // Hillis-Steele inclusive scan across threads
    for (int off = 1; off < 256; off <<= 1) {
        int v = (tid >= off) ? sd[tid - off] : 0;
        __syncthreads();
        sd[tid] += v;
        __syncthreads();
    }
    const int texcl = sd[tid] - s;
    const int boff = partials[blockIdx.x];
#pragma unroll
    for (int j = 0; j < SCAN_PER; ++j) {
        int i = base + j;
        if (i < n) {
            int rp = boff + texcl + loc[j];
            row_ptr[i] = rp;
            cursor[i] = rp;
        }
    }
}

// Bin edges by dst: rec[pos] = {src, bits(norm)}.
__global__ __launch_bounds__(256) void k_scatter(const void* __restrict__ eidx, int E,
                                                 const int* __restrict__ flag,
                                                 const float* __restrict__ dinv,
                                                 int* __restrict__ cursor,
                                                 int2* __restrict__ rec) {
    int e = blockIdx.x * 256 + threadIdx.x;
    if (e >= E) return;
    int s, d;
    if (*flag) {
        s = (int)((const long long*)eidx)[e];
        d = (int)((const long long*)eidx)[E + e];
    } else {
        s = ((const int*)eidx)[e];
        d = ((const int*)eidx)[E + e];
    }
    float nrm = dinv[s] * dinv[d];
    int pos = atomicAdd(&cursor[d], 1);
    rec[pos] = make_int2(s, __float_as_int(nrm));
}

// Y[n,128] = X[n,128] @ W[128,128], f32, W + X tile staged in LDS.
__global__ __launch_bounds__(256) void k_gemm(const float* __restrict__ X,
                                              const float* __restrict__ W,
                                              float* __restrict__ Y, int n) {
    __shared__ float Ws[128 * 128];
    __shared__ float Xs[64 * 128];
    const int tid = threadIdx.x;
    for (int i = tid; i < 128 * 32; i += 256)
        ((float4*)Ws)[i] = ((const float4*)W)[i];
    const int row0 = blockIdx.x * 64;
    for (int i = tid; i < 64 * 32; i += 256) {
        int r = i >> 5, c = i & 31;
        int gr = row0 + r;
        float4 v = (gr < n) ? ((const float4*)X)[(size_t)gr * 32 + c]
                            : float4{0.f, 0.f, 0.f, 0.f};
        ((float4*)Xs)[i] = v;
    }
    __syncthreads();
    const int c4 = (tid & 31) * 4;
    const int rb = tid >> 5;
    float4 acc[8];
#pragma unroll
    for (int j = 0; j < 8; ++j) acc[j] = float4{0.f, 0.f, 0.f, 0.f};
    for (int k = 0; k < 128; ++k) {
        float4 w = *(const float4*)&Ws[k * 128 + c4];
#pragma unroll
        for (int j = 0; j < 8; ++j) {
            float xv = Xs[(rb + 8 * j) * 128 + k];
            acc[j].x = fmaf(xv, w.x, acc[j].x);
            acc[j].y = fmaf(xv, w.y, acc[j].y);
            acc[j].z = fmaf(xv, w.z, acc[j].z);
            acc[j].w = fmaf(xv, w.w, acc[j].w);
        }
    }
#pragma unroll
    for (int j = 0; j < 8; ++j) {
        int r = row0 + rb + 8 * j;
        if (r < n) *(float4*)&Y[(size_t)r * 128 + c4] = acc[j];
    }
}

// One wave per dst row: B[d] = H[d]*dinv[d]^2 + bias + sum_{e in bucket} H[src_e]*norm_e
__global__ __launch_bounds__(256) void k_agg(const int2* __restrict__ rec,
                                             const int* __restrict__ row_ptr,
                                             const float* __restrict__ H,
                                             const float* __restrict__ dinv,
                                             const float* __restrict__ bias,
                                             float* __restrict__ B, int n) {
    const int d = blockIdx.x * 4 + (threadIdx.x >> 6);
    if (d >= n) return;
    const int lane = threadIdx.x & 63;
    float s = dinv[d];
    s *= s;
    float2 h = ((const float2*)(H + (size_t)d * 128))[lane];
    float2 bb = ((const float2*)bias)[lane];
    float2 acc{fmaf(h.x, s, bb.x), fmaf(h.y, s, bb.y)};
    int e = row_ptr[d];
    const int end = row_ptr[d + 1];
    for (; e + 1 < end; e += 2) {
        int2 r0 = rec[e], r1 = rec[e + 1];
        float2 h0 = ((const float2*)(H + (size_t)r0.x * 128))[lane];
        float2 h1 = ((const float2*)(H + (size_t)r1.x * 128))[lane];
        float n0 = __int_as_float(r0.y), n1 = __int_as_float(r1.y);
        acc.x = fmaf(h0.x, n0, acc.x);
        acc.y = fmaf(h0.y, n0, acc.y);
        acc.x = fmaf(h1.x, n1, acc.x);
        acc.y = fmaf(h1.y, n1, acc.y);
    }
    if (e < end) {
        int2 r0 = rec[e];
        float2 h0 = ((const float2*)(H + (size_t)r0.x * 128))[lane];
        float n0 = __int_as_float(r0.y);
        acc.x = fmaf(h0.x, n0, acc.x);
        acc.y = fmaf(h0.y, n0, acc.y);
    }
    ((float2*)(B + (size_t)d * 128))[lane] = acc;
}

// ---- fallback (atomic) path kernels ----
__global__ __launch_bounds__(256) void k_selfloop(const float* __restrict__ H,
                                                  const float* __restrict__ dinv,
                                                  const float* __restrict__ bias,
                                                  float* __restrict__ B, int n) {
    int idx = blockIdx.x * 256 + threadIdx.x;
    int total = n * 32;
    if (idx >= total) return;
    int r = idx >> 5, c = idx & 31;
    float s = dinv[r];
    s *= s;
    float4 h = ((const float4*)H)[idx];
    float4 bb = ((const float4*)bias)[c];
    float4 o{fmaf(h.x, s, bb.x), fmaf(h.y, s, bb.y),
             fmaf(h.z, s, bb.z), fmaf(h.w, s, bb.w)};
    ((float4*)B)[idx] = o;
}

__global__ __launch_bounds__(256) void k_edge(const void* __restrict__ eidx, int E,
                                              const int* __restrict__ flag,
                                              const float* __restrict__ dinv,
                                              const float* __restrict__ H,
                                              float* __restrict__ B) {
    int e = blockIdx.x * 8 + (threadIdx.x >> 5);
    if (e >= E) return;
    int lane = threadIdx.x & 31;
    int s, d;
    if (*flag) {
        s = (int)((const long long*)eidx)[e];
        d = (int)((const long long*)eidx)[E + e];
    } else {
        s = ((const int*)eidx)[e];
        d = ((const int*)eidx)[E + e];
    }
    float nrm = dinv[s] * dinv[d];
    float4 h = ((const float4*)(H + (size_t)s * 128))[lane];
    float* out = B + (size_t)d * 128 + lane * 4;
    atomicAdd(out + 0, h.x * nrm);
    atomicAdd(out + 1, h.y * nrm);
    atomicAdd(out + 2, h.z * nrm);
    atomicAdd(out + 3, h.w * nrm);
}

// Column sums / sumsq into stats[0:128]=sum, stats[128:256]=sumsq (pre-zeroed).
__global__ __launch_bounds__(256) void k_bnstats(const float* __restrict__ B, int n,
                                                 float* __restrict__ stats) {
    __shared__ float rs[256], rss[256];
    int col = threadIdx.x & 127;
    int rg = threadIdx.x >> 7;
    float s = 0.f, ss = 0.f;
    for (int r = blockIdx.x * 2 + rg; r < n; r += gridDim.x * 2) {
        float v = B[(size_t)r * 128 + col];
        s += v;
        ss = fmaf(v, v, ss);
    }
    rs[threadIdx.x] = s;
    rss[threadIdx.x] = ss;
    __syncthreads();
    if (threadIdx.x < 128) {
        atomicAdd(&stats[col], rs[threadIdx.x] + rs[threadIdx.x + 128]);
        atomicAdd(&stats[128 + col], rss[threadIdx.x] + rss[threadIdx.x + 128]);
    }
}

__global__ __launch_bounds__(256) void k_bnapply(const float* __restrict__ Bin,
                                                 float* __restrict__ out,
                                                 const float* __restrict__ stats,
                                                 const float* __restrict__ gamma,
                                                 const float* __restrict__ beta,
                                                 int n, float invn) {
    int idx = blockIdx.x * 256 + threadIdx.x;
    int total = n * 32;
    if (idx >= total) return;
    int c4 = (idx & 31) * 4;
    float4 x = ((const float4*)Bin)[idx];
    float4 o;
#pragma unroll
    for (int j = 0; j < 4; ++j) {
        int c = c4 + j;
        float m = stats[c] * invn;
        float var = fmaf(-m, m, stats[128 + c] * invn);
        float sc = rsqrtf(var + BN_EPS) * gamma[c];
        float sh = fmaf(-m, sc, beta[c]);
        float v = fmaf((&x.x)[j], sc, sh);
        (&o.x)[j] = fmaxf(v, 0.f);
    }
    ((float4*)out)[idx] = o;
}

extern "C" void kernel_launch(void* const* d_in, const int* in_sizes, int n_in,
                              void* d_out, int out_size, void* d_ws, size_t ws_size,
                              hipStream_t stream) {
    const float* x   = (const float*)d_in[0];
    const void*  ei  = d_in[1];
    const float* W1  = (const float*)d_in[2];
    const float* b1  = (const float*)d_in[3];
    const float* g1  = (const float*)d_in[4];
    const float* be1 = (const float*)d_in[5];
    const float* W2  = (const float*)d_in[6];
    const float* b2  = (const float*)d_in[7];
    const float* g2  = (const float*)d_in[8];
    const float* be2 = (const float*)d_in[9];

    const int n = in_sizes[0] / 128;
    const int E = in_sizes[1] / 2;
    const float invn = 1.0f / (float)n;
    const int nb_scan = (n + SCAN_TILE - 1) / SCAN_TILE;

    char* p = (char*)d_ws;
    float* A = (float*)p;            p += (size_t)n * 128 * 4;
    float* B = (float*)p;            p += (size_t)n * 128 * 4;
    int2*  rec = (int2*)p;           p += (size_t)E * 8;
    int*   row_ptr = (int*)p;        p += (size_t)(n + 1) * 4;
    int*   cursor = (int*)p;         p += (size_t)n * 4;
    int*   deg = (int*)p;            p += (size_t)n * 4;
    float* dinv = (float*)p;         p += (size_t)n * 4;
    float* stats = (float*)p;        p += 256 * 4;
    int*   flag = (int*)p;           p += 16;
    int*   partials = (int*)p;       p += (size_t)nb_scan * 4;
    const size_t needed = (size_t)(p - (char*)d_ws);
    const bool csr_ok = needed <= ws_size;
    float* out = (float*)d_out;

    const int nb_n    = (n + 255) / 256;
    const int nb_e    = (E + 255) / 256;
    const int nb_el   = (n * 32 + 255) / 256;
    const int nb_gm   = (n + 63) / 64;
    const int nb_edge = (E + 7) / 8;
    const int nb_agg  = (n + 3) / 4;

    k_detect_i64<<<1, 256, 0, stream>>>((const unsigned*)ei, flag);
    k_init_deg<<<nb_n, 256, 0, stream>>>(deg, n);
    k_count_deg<<<nb_e, 256, 0, stream>>>(ei, E, flag, deg);
    k_dinv<<<nb_n, 256, 0, stream>>>(deg, dinv, n);

    if (csr_ok) {
        k_scan1<<<nb_scan, 256, 0, stream>>>(deg, n, partials);
        k_scan2<<<1, 64, 0, stream>>>(partials, nb_scan, row_ptr + n);
        k_scan3<<<nb_scan, 256, 0, stream>>>(deg, n, partials, row_ptr, cursor);
        k_scatter<<<nb_e, 256, 0, stream>>>(ei, E, flag, dinv, cursor, rec);

        // ---- layer 1 ----
        k_gemm<<<nb_gm, 256, 0, stream>>>(x, W1, A, n);
        k_agg<<<nb_agg, 256, 0, stream>>>(rec, row_ptr, A, dinv, b1, B, n);
        hipMemsetAsync(stats, 0, 256 * sizeof(float), stream);
        k_bnstats<<<256, 256, 0, stream>>>(B, n, stats);
        k_bnapply<<<nb_el, 256, 0, stream>>>(B, B, stats, g1, be1, n, invn);

        // ---- layer 2 ----
        k_gemm<<<nb_gm, 256, 0, stream>>>(B, W2, A, n);
        k_agg<<<nb_agg, 256, 0, stream>>>(rec, row_ptr, A, dinv, b2, B, n);
        hipMemsetAsync(stats, 0, 256 * sizeof(float), stream);
        k_bnstats<<<256, 256, 0, stream>>>(B, n, stats);
        k_bnapply<<<nb_el, 256, 0, stream>>>(B, out, stats, g2, be2, n, invn);
    } else {
        // fallback: atomic scatter path (R0)
        k_gemm<<<nb_gm, 256, 0, stream>>>(x, W1, A, n);
        k_selfloop<<<nb_el, 256, 0, stream>>>(A, dinv, b1, B, n);
        k_edge<<<nb_edge, 256, 0, stream>>>(ei, E, flag, dinv, A, B);
        hipMemsetAsync(stats, 0, 256 * sizeof(float), stream);
        k_bnstats<<<256, 256, 0, stream>>>(B, n, stats);
        k_bnapply<<<nb_el, 256, 0, stream>>>(B, B, stats, g1, be1, n, invn);

        k_gemm<<<nb_gm, 256, 0, stream>>>(B, W2, A, n);
        k_selfloop<<<nb_el, 256, 0, stream>>>(A, dinv, b2, B, n);
        k_edge<<<nb_edge, 256, 0, stream>>>(ei, E, flag, dinv, A, B);
        hipMemsetAsync(stats, 0, 256 * sizeof(float), stream);
        k_bnstats<<<256, 256, 0, stream>>>(B, n, stats);
        k_bnapply<<<nb_el, 256, 0, stream>>>(B, out, stats, g2, be2, n, invn);
    }
}

// Round 4
// 364.617 us; speedup vs baseline: 8.0481x; 1.1829x over previous
//
#include <hip/hip_runtime.h>

static constexpr float BN_EPS = 1e-5f;

#define SCAN_PER 8
#define SCAN_TILE 2048  // 256 threads * 8

// Detect whether edge_index is int64 (high words all zero) or int32.
__global__ __launch_bounds__(256) void k_detect_i64(const unsigned* __restrict__ ei,
                                                    int* __restrict__ flag) {
    if (blockIdx.x == 0 && threadIdx.x == 0) {
        int allz = 1;
        for (int i = 0; i < 256; ++i) {
            if (ei[2 * i + 1] != 0u) { allz = 0; break; }
        }
        *flag = allz;
    }
}

__global__ __launch_bounds__(256) void k_init_deg(int* __restrict__ deg, int n) {
    int i = blockIdx.x * 256 + threadIdx.x;
    if (i < n) deg[i] = 1;  // self loop
}

__global__ __launch_bounds__(256) void k_count_deg(const void* __restrict__ eidx, int E,
                                                   const int* __restrict__ flag,
                                                   int* __restrict__ deg) {
    int e = blockIdx.x * 256 + threadIdx.x;
    if (e >= E) return;
    int d;
    if (*flag) d = (int)((const long long*)eidx)[E + e];
    else       d = ((const int*)eidx)[E + e];
    atomicAdd(&deg[d], 1);
}

__global__ __launch_bounds__(256) void k_dinv(const int* __restrict__ deg,
                                              float* __restrict__ dinv, int n) {
    int i = blockIdx.x * 256 + threadIdx.x;
    if (i < n) dinv[i] = rsqrtf((float)deg[i]);
}

// ---- two-level parallel exclusive scan of (deg[i]-1); also emits dinv ----
__global__ __launch_bounds__(256) void k_scan1(const int* __restrict__ deg, int n,
                                               int* __restrict__ partials,
                                               float* __restrict__ dinv) {
    __shared__ int sd[256];
    const int tid = threadIdx.x;
    const int base = blockIdx.x * SCAN_TILE + tid * SCAN_PER;
    int s = 0;
#pragma unroll
    for (int j = 0; j < SCAN_PER; ++j) {
        int i = base + j;
        if (i < n) {
            int dg = deg[i];
            s += dg - 1;
            dinv[i] = rsqrtf((float)dg);
        }
    }
    sd[tid] = s;
    __syncthreads();
    for (int off = 128; off > 0; off >>= 1) {
        if (tid < off) sd[tid] += sd[tid + off];
        __syncthreads();
    }
    if (tid == 0) partials[blockIdx.x] = sd[0];
}

__global__ __launch_bounds__(64) void k_scan2(int* __restrict__ partials, int nb,
                                              int* __restrict__ total_out) {
    if (threadIdx.x == 0 && blockIdx.x == 0) {
        int run = 0;
        for (int b = 0; b < nb; ++b) {
            int t = partials[b];
            partials[b] = run;
            run += t;
        }
        *total_out = run;  // row_ptr[n]
    }
}

__global__ __launch_bounds__(256) void k_scan3(const int* __restrict__ deg, int n,
                                               const int* __restrict__ partials,
                                               int* __restrict__ row_ptr,
                                               int* __restrict__ cursor) {
    __shared__ int sd[256];
    const int tid = threadIdx.x;
    const int base = blockIdx.x * SCAN_TILE + tid * SCAN_PER;
    int loc[SCAN_PER];
    int s = 0;
#pragma unroll
    for (int j = 0; j < SCAN_PER; ++j) {
        int i = base + j;
        int v = (i < n) ? deg[i] - 1 : 0;
        loc[j] = s;
        s += v;
    }
    sd[tid] = s;
    __syncthreads();
    for (int off = 1; off < 256; off <<= 1) {
        int v = (tid >= off) ? sd[tid - off] : 0;
        __syncthreads();
        sd[tid] += v;
        __syncthreads();
    }
    const int texcl = sd[tid] - s;
    const int boff = partials[blockIdx.x];
#pragma unroll
    for (int j = 0; j < SCAN_PER; ++j) {
        int i = base + j;
        if (i < n) {
            int rp = boff + texcl + loc[j];
            row_ptr[i] = rp;
            cursor[i] = rp;
        }
    }
}

// Bin edges by dst: rec[pos] = {src, bits(norm)}.
__global__ __launch_bounds__(256) void k_scatter(const void* __restrict__ eidx, int E,
                                                 const int* __restrict__ flag,
                                                 const float* __restrict__ dinv,
                                                 int* __restrict__ cursor,
                                                 int2* __restrict__ rec) {
    int e = blockIdx.x * 256 + threadIdx.x;
    if (e >= E) return;
    int s, d;
    if (*flag) {
        s = (int)((const long long*)eidx)[e];
        d = (int)((const long long*)eidx)[E + e];
    } else {
        s = ((const int*)eidx)[e];
        d = ((const int*)eidx)[E + e];
    }
    float nrm = dinv[s] * dinv[d];
    int pos = atomicAdd(&cursor[d], 1);
    rec[pos] = make_int2(s, __float_as_int(nrm));
}

// Y[n,128] = act(X)[n,128] @ W[128,128], f32.
// If scale != nullptr, act(x) = relu(x*scale[col] + shift[col]) applied while
// staging the X tile (folded BN+ReLU of the previous layer).
// LDS = 64K (W) + 16K (32-row X tile) = 80 KiB -> 2 blocks/CU.
__global__ __launch_bounds__(256) void k_gemm(const float* __restrict__ X,
                                              const float* __restrict__ W,
                                              float* __restrict__ Y, int n,
                                              const float* __restrict__ scale,
                                              const float* __restrict__ shift) {
    __shared__ float Ws[128 * 128];  // 64 KiB
    __shared__ float Xs[32 * 128];   // 16 KiB
    const int tid = threadIdx.x;
    for (int i = tid; i < 128 * 32; i += 256)
        ((float4*)Ws)[i] = ((const float4*)W)[i];
    const int row0 = blockIdx.x * 32;
    if (scale) {
        for (int i = tid; i < 32 * 32; i += 256) {
            int r = i >> 5, c = i & 31;
            int gr = row0 + r;
            float4 v = (gr < n) ? ((const float4*)X)[(size_t)gr * 32 + c]
                                : float4{0.f, 0.f, 0.f, 0.f};
            float4 sc = ((const float4*)scale)[c];
            float4 sh = ((const float4*)shift)[c];
            v.x = fmaxf(fmaf(v.x, sc.x, sh.x), 0.f);
            v.y = fmaxf(fmaf(v.y, sc.y, sh.y), 0.f);
            v.z = fmaxf(fmaf(v.z, sc.z, sh.z), 0.f);
            v.w = fmaxf(fmaf(v.w, sc.w, sh.w), 0.f);
            ((float4*)Xs)[i] = v;
        }
    } else {
        for (int i = tid; i < 32 * 32; i += 256) {
            int r = i >> 5, c = i & 31;
            int gr = row0 + r;
            float4 v = (gr < n) ? ((const float4*)X)[(size_t)gr * 32 + c]
                                : float4{0.f, 0.f, 0.f, 0.f};
            ((float4*)Xs)[i] = v;
        }
    }
    __syncthreads();
    const int c4 = (tid & 31) * 4;
    const int rb = tid >> 5;  // 0..7; thread owns rows rb+8j, j=0..3
    float4 acc[4];
#pragma unroll
    for (int j = 0; j < 4; ++j) acc[j] = float4{0.f, 0.f, 0.f, 0.f};
    for (int k = 0; k < 128; ++k) {
        float4 w = *(const float4*)&Ws[k * 128 + c4];
#pragma unroll
        for (int j = 0; j < 4; ++j) {
            float xv = Xs[(rb + 8 * j) * 128 + k];
            acc[j].x = fmaf(xv, w.x, acc[j].x);
            acc[j].y = fmaf(xv, w.y, acc[j].y);
            acc[j].z = fmaf(xv, w.z, acc[j].z);
            acc[j].w = fmaf(xv, w.w, acc[j].w);
        }
    }
#pragma unroll
    for (int j = 0; j < 4; ++j) {
        int r = row0 + rb + 8 * j;
        if (r < n) *(float4*)&Y[(size_t)r * 128 + c4] = acc[j];
    }
}

// One wave per dst row: B[d] = H[d]*dinv[d]^2 + bias + sum_{e} H[src_e]*norm_e
// 4-edge unroll -> 4 independent gathers in flight; scalar rec loads.
__global__ __launch_bounds__(256) void k_agg(const int2* __restrict__ rec,
                                             const int* __restrict__ row_ptr,
                                             const float* __restrict__ H,
                                             const float* __restrict__ dinv,
                                             const float* __restrict__ bias,
                                             float* __restrict__ B, int n) {
    const int d = blockIdx.x * 4 + (threadIdx.x >> 6);
    if (d >= n) return;
    const int lane = threadIdx.x & 63;
    float s = dinv[d];
    s *= s;
    float2 h = ((const float2*)(H + (size_t)d * 128))[lane];
    float2 bb = ((const float2*)bias)[lane];
    float accx = fmaf(h.x, s, bb.x);
    float accy = fmaf(h.y, s, bb.y);
    int e = __builtin_amdgcn_readfirstlane(row_ptr[d]);
    const int end = __builtin_amdgcn_readfirstlane(row_ptr[d + 1]);
    if ((e & 1) && e < end) {  // align to 16B for int4 loads
        int2 r0 = rec[e];
        float2 h0 = ((const float2*)(H + (size_t)r0.x * 128))[lane];
        float n0 = __int_as_float(r0.y);
        accx = fmaf(h0.x, n0, accx);
        accy = fmaf(h0.y, n0, accy);
        ++e;
    }
    for (; e + 3 < end; e += 4) {
        int4 ra = *(const int4*)&rec[e];
        int4 rb = *(const int4*)&rec[e + 2];
        float2 h0 = ((const float2*)(H + (size_t)ra.x * 128))[lane];
        float2 h1 = ((const float2*)(H + (size_t)ra.z * 128))[lane];
        float2 h2 = ((const float2*)(H + (size_t)rb.x * 128))[lane];
        float2 h3 = ((const float2*)(H + (size_t)rb.z * 128))[lane];
        float n0 = __int_as_float(ra.y), n1 = __int_as_float(ra.w);
        float n2 = __int_as_float(rb.y), n3 = __int_as_float(rb.w);
        accx = fmaf(h0.x, n0, accx); accy = fmaf(h0.y, n0, accy);
        accx = fmaf(h1.x, n1, accx); accy = fmaf(h1.y, n1, accy);
        accx = fmaf(h2.x, n2, accx); accy = fmaf(h2.y, n2, accy);
        accx = fmaf(h3.x, n3, accx); accy = fmaf(h3.y, n3, accy);
    }
    for (; e < end; ++e) {
        int2 r0 = rec[e];
        float2 h0 = ((const float2*)(H + (size_t)r0.x * 128))[lane];
        float n0 = __int_as_float(r0.y);
        accx = fmaf(h0.x, n0, accx);
        accy = fmaf(h0.y, n0, accy);
    }
    ((float2*)(B + (size_t)d * 128))[lane] = make_float2(accx, accy);
}

// Fold BN affine: scale[c] = gamma*rsqrt(var+eps), shift[c] = beta - mean*scale
__global__ __launch_bounds__(128) void k_bnfold(const float* __restrict__ stats,
                                                const float* __restrict__ gamma,
                                                const float* __restrict__ beta,
                                                float invn,
                                                float* __restrict__ scale,
                                                float* __restrict__ shift) {
    int c = threadIdx.x;
    float m = stats[c] * invn;
    float var = fmaf(-m, m, stats[128 + c] * invn);
    float sc = rsqrtf(var + BN_EPS) * gamma[c];
    scale[c] = sc;
    shift[c] = fmaf(-m, sc, beta[c]);
}

// ---- fallback (atomic) path kernels ----
__global__ __launch_bounds__(256) void k_selfloop(const float* __restrict__ H,
                                                  const float* __restrict__ dinv,
                                                  const float* __restrict__ bias,
                                                  float* __restrict__ B, int n) {
    int idx = blockIdx.x * 256 + threadIdx.x;
    int total = n * 32;
    if (idx >= total) return;
    int r = idx >> 5, c = idx & 31;
    float s = dinv[r];
    s *= s;
    float4 h = ((const float4*)H)[idx];
    float4 bb = ((const float4*)bias)[c];
    float4 o{fmaf(h.x, s, bb.x), fmaf(h.y, s, bb.y),
             fmaf(h.z, s, bb.z), fmaf(h.w, s, bb.w)};
    ((float4*)B)[idx] = o;
}

__global__ __launch_bounds__(256) void k_edge(const void* __restrict__ eidx, int E,
                                              const int* __restrict__ flag,
                                              const float* __restrict__ dinv,
                                              const float* __restrict__ H,
                                              float* __restrict__ B) {
    int e = blockIdx.x * 8 + (threadIdx.x >> 5);
    if (e >= E) return;
    int lane = threadIdx.x & 31;
    int s, d;
    if (*flag) {
        s = (int)((const long long*)eidx)[e];
        d = (int)((const long long*)eidx)[E + e];
    } else {
        s = ((const int*)eidx)[e];
        d = ((const int*)eidx)[E + e];
    }
    float nrm = dinv[s] * dinv[d];
    float4 h = ((const float4*)(H + (size_t)s * 128))[lane];
    float* out = B + (size_t)d * 128 + lane * 4;
    atomicAdd(out + 0, h.x * nrm);
    atomicAdd(out + 1, h.y * nrm);
    atomicAdd(out + 2, h.z * nrm);
    atomicAdd(out + 3, h.w * nrm);
}

// Column sums / sumsq into stats[0:128]=sum, stats[128:256]=sumsq (pre-zeroed).
__global__ __launch_bounds__(256) void k_bnstats(const float* __restrict__ B, int n,
                                                 float* __restrict__ stats) {
    __shared__ float rs[256], rss[256];
    int col = threadIdx.x & 127;
    int rg = threadIdx.x >> 7;
    float s = 0.f, ss = 0.f;
    for (int r = blockIdx.x * 2 + rg; r < n; r += gridDim.x * 2) {
        float v = B[(size_t)r * 128 + col];
        s += v;
        ss = fmaf(v, v, ss);
    }
    rs[threadIdx.x] = s;
    rss[threadIdx.x] = ss;
    __syncthreads();
    if (threadIdx.x < 128) {
        atomicAdd(&stats[col], rs[threadIdx.x] + rs[threadIdx.x + 128]);
        atomicAdd(&stats[128 + col], rss[threadIdx.x] + rss[threadIdx.x + 128]);
    }
}

__global__ __launch_bounds__(256) void k_bnapply(const float* __restrict__ Bin,
                                                 float* __restrict__ out,
                                                 const float* __restrict__ stats,
                                                 const float* __restrict__ gamma,
                                                 const float* __restrict__ beta,
                                                 int n, float invn) {
    int idx = blockIdx.x * 256 + threadIdx.x;
    int total = n * 32;
    if (idx >= total) return;
    int c4 = (idx & 31) * 4;
    float4 x = ((const float4*)Bin)[idx];
    float4 o;
#pragma unroll
    for (int j = 0; j < 4; ++j) {
        int c = c4 + j;
        float m = stats[c] * invn;
        float var = fmaf(-m, m, stats[128 + c] * invn);
        float sc = rsqrtf(var + BN_EPS) * gamma[c];
        float sh = fmaf(-m, sc, beta[c]);
        float v = fmaf((&x.x)[j], sc, sh);
        (&o.x)[j] = fmaxf(v, 0.f);
    }
    ((float4*)out)[idx] = o;
}

static inline char* align256(char* p) {
    return (char*)(((uintptr_t)p + 255) & ~(uintptr_t)255);
}

extern "C" void kernel_launch(void* const* d_in, const int* in_sizes, int n_in,
                              void* d_out, int out_size, void* d_ws, size_t ws_size,
                              hipStream_t stream) {
    const float* x   = (const float*)d_in[0];
    const void*  ei  = d_in[1];
    const float* W1  = (const float*)d_in[2];
    const float* b1  = (const float*)d_in[3];
    const float* g1  = (const float*)d_in[4];
    const float* be1 = (const float*)d_in[5];
    const float* W2  = (const float*)d_in[6];
    const float* b2  = (const float*)d_in[7];
    const float* g2  = (const float*)d_in[8];
    const float* be2 = (const float*)d_in[9];

    const int n = in_sizes[0] / 128;
    const int E = in_sizes[1] / 2;
    const float invn = 1.0f / (float)n;
    const int nb_scan = (n + SCAN_TILE - 1) / SCAN_TILE;

    char* p = (char*)d_ws;
    float* A = (float*)p;            p += (size_t)n * 128 * 4;
    float* B = (float*)p;            p += (size_t)n * 128 * 4;
    int2*  rec = (int2*)p;           p += (size_t)E * 8;        // 16B-aligned base
    int*   row_ptr = (int*)p;        p += (size_t)(n + 1) * 4;
    p = align256(p);
    int*   cursor = (int*)p;         p += (size_t)n * 4;
    p = align256(p);
    int*   deg = (int*)p;            p += (size_t)n * 4;
    p = align256(p);
    float* dinv = (float*)p;         p += (size_t)n * 4;
    p = align256(p);
    float* stats = (float*)p;        p += 256 * 4;
    float* scale = (float*)p;        p += 128 * 4;
    float* shift = (float*)p;        p += 128 * 4;
    int*   flag = (int*)p;           p += 16;
    int*   partials = (int*)p;       p += (size_t)nb_scan * 4;
    const size_t needed = (size_t)(p - (char*)d_ws);
    const bool csr_ok = needed <= ws_size;
    float* out = (float*)d_out;

    const int nb_n    = (n + 255) / 256;
    const int nb_e    = (E + 255) / 256;
    const int nb_el   = (n * 32 + 255) / 256;
    const int nb_gm   = (n + 31) / 32;
    const int nb_edge = (E + 7) / 8;
    const int nb_agg  = (n + 3) / 4;

    k_detect_i64<<<1, 256, 0, stream>>>((const unsigned*)ei, flag);
    k_init_deg<<<nb_n, 256, 0, stream>>>(deg, n);
    k_count_deg<<<nb_e, 256, 0, stream>>>(ei, E, flag, deg);

    if (csr_ok) {
        k_scan1<<<nb_scan, 256, 0, stream>>>(deg, n, partials, dinv);
        k_scan2<<<1, 64, 0, stream>>>(partials, nb_scan, row_ptr + n);
        k_scan3<<<nb_scan, 256, 0, stream>>>(deg, n, partials, row_ptr, cursor);
        k_scatter<<<nb_e, 256, 0, stream>>>(ei, E, flag, dinv, cursor, rec);

        // ---- layer 1 ----
        k_gemm<<<nb_gm, 256, 0, stream>>>(x, W1, A, n, nullptr, nullptr);
        k_agg<<<nb_agg, 256, 0, stream>>>(rec, row_ptr, A, dinv, b1, B, n);
        hipMemsetAsync(stats, 0, 256 * sizeof(float), stream);
        k_bnstats<<<256, 256, 0, stream>>>(B, n, stats);
        k_bnfold<<<1, 128, 0, stream>>>(stats, g1, be1, invn, scale, shift);

        // ---- layer 2 (BN1+ReLU folded into GEMM staging) ----
        k_gemm<<<nb_gm, 256, 0, stream>>>(B, W2, A, n, scale, shift);
        k_agg<<<nb_agg, 256, 0, stream>>>(rec, row_ptr, A, dinv, b2, B, n);
        hipMemsetAsync(stats, 0, 256 * sizeof(float), stream);
        k_bnstats<<<256, 256, 0, stream>>>(B, n, stats);
        k_bnapply<<<nb_el, 256, 0, stream>>>(B, out, stats, g2, be2, n, invn);
    } else {
        // fallback: atomic scatter path
        k_dinv<<<nb_n, 256, 0, stream>>>(deg, dinv, n);
        k_gemm<<<nb_gm, 256, 0, stream>>>(x, W1, A, n, nullptr, nullptr);
        k_selfloop<<<nb_el, 256, 0, stream>>>(A, dinv, b1, B, n);
        k_edge<<<nb_edge, 256, 0, stream>>>(ei, E, flag, dinv, A, B);
        hipMemsetAsync(stats, 0, 256 * sizeof(float), stream);
        k_bnstats<<<256, 256, 0, stream>>>(B, n, stats);
        k_bnapply<<<nb_el, 256, 0, stream>>>(B, B, stats, g1, be1, n, invn);

        k_gemm<<<nb_gm, 256, 0, stream>>>(B, W2, A, n, nullptr, nullptr);
        k_selfloop<<<nb_el, 256, 0, stream>>>(A, dinv, b2, B, n);
        k_edge<<<nb_edge, 256, 0, stream>>>(ei, E, flag, dinv, A, B);
        hipMemsetAsync(stats, 0, 256 * sizeof(float), stream);
        k_bnstats<<<256, 256, 0, stream>>>(B, n, stats);
        k_bnapply<<<nb_el, 256, 0, stream>>>(B, out, stats, g2, be2, n, invn);
    }
}

// Round 5
// 318.530 us; speedup vs baseline: 9.2125x; 1.1447x over previous
//
#include <hip/hip_runtime.h>

static constexpr float BN_EPS = 1e-5f;

#define SCAN_PER 8
#define SCAN_TILE 2048  // 256 threads * 8

__device__ __forceinline__ unsigned rne_bf16(float f) {
    unsigned u = __float_as_uint(f);
    u += 0x7fffu + ((u >> 16) & 1u);
    return u >> 16;
}

// Detect whether edge_index is int64 (high words all zero) or int32.
__global__ __launch_bounds__(256) void k_detect_i64(const unsigned* __restrict__ ei,
                                                    int* __restrict__ flag) {
    if (blockIdx.x == 0 && threadIdx.x == 0) {
        int allz = 1;
        for (int i = 0; i < 256; ++i) {
            if (ei[2 * i + 1] != 0u) { allz = 0; break; }
        }
        *flag = allz;
    }
}

__global__ __launch_bounds__(256) void k_init_deg(int* __restrict__ deg, int n) {
    int i = blockIdx.x * 256 + threadIdx.x;
    if (i < n) deg[i] = 1;  // self loop
}

__global__ __launch_bounds__(256) void k_count_deg(const void* __restrict__ eidx, int E,
                                                   const int* __restrict__ flag,
                                                   int* __restrict__ deg) {
    int e = blockIdx.x * 256 + threadIdx.x;
    if (e >= E) return;
    int d;
    if (*flag) d = (int)((const long long*)eidx)[E + e];
    else       d = ((const int*)eidx)[E + e];
    atomicAdd(&deg[d], 1);
}

__global__ __launch_bounds__(256) void k_dinv(const int* __restrict__ deg,
                                              float* __restrict__ dinv, int n) {
    int i = blockIdx.x * 256 + threadIdx.x;
    if (i < n) dinv[i] = rsqrtf((float)deg[i]);
}

// ---- two-level parallel exclusive scan of (deg[i]-1); also emits dinv ----
__global__ __launch_bounds__(256) void k_scan1(const int* __restrict__ deg, int n,
                                               int* __restrict__ partials,
                                               float* __restrict__ dinv) {
    __shared__ int sd[256];
    const int tid = threadIdx.x;
    const int base = blockIdx.x * SCAN_TILE + tid * SCAN_PER;
    int s = 0;
#pragma unroll
    for (int j = 0; j < SCAN_PER; ++j) {
        int i = base + j;
        if (i < n) {
            int dg = deg[i];
            s += dg - 1;
            dinv[i] = rsqrtf((float)dg);
        }
    }
    sd[tid] = s;
    __syncthreads();
    for (int off = 128; off > 0; off >>= 1) {
        if (tid < off) sd[tid] += sd[tid + off];
        __syncthreads();
    }
    if (tid == 0) partials[blockIdx.x] = sd[0];
}

__global__ __launch_bounds__(64) void k_scan2(int* __restrict__ partials, int nb,
                                              int* __restrict__ total_out) {
    if (threadIdx.x == 0 && blockIdx.x == 0) {
        int run = 0;
        for (int b = 0; b < nb; ++b) {
            int t = partials[b];
            partials[b] = run;
            run += t;
        }
        *total_out = run;  // row_ptr[n]
    }
}

__global__ __launch_bounds__(256) void k_scan3(const int* __restrict__ deg, int n,
                                               const int* __restrict__ partials,
                                               int* __restrict__ row_ptr,
                                               int* __restrict__ cursor) {
    __shared__ int sd[256];
    const int tid = threadIdx.x;
    const int base = blockIdx.x * SCAN_TILE + tid * SCAN_PER;
    int loc[SCAN_PER];
    int s = 0;
#pragma unroll
    for (int j = 0; j < SCAN_PER; ++j) {
        int i = base + j;
        int v = (i < n) ? deg[i] - 1 : 0;
        loc[j] = s;
        s += v;
    }
    sd[tid] = s;
    __syncthreads();
    for (int off = 1; off < 256; off <<= 1) {
        int v = (tid >= off) ? sd[tid - off] : 0;
        __syncthreads();
        sd[tid] += v;
        __syncthreads();
    }
    const int texcl = sd[tid] - s;
    const int boff = partials[blockIdx.x];
#pragma unroll
    for (int j = 0; j < SCAN_PER; ++j) {
        int i = base + j;
        if (i < n) {
            int rp = boff + texcl + loc[j];
            row_ptr[i] = rp;
            cursor[i] = rp;
        }
    }
}

// Bin edges by dst: rec[pos] = {src, bits(norm)}.
__global__ __launch_bounds__(256) void k_scatter(const void* __restrict__ eidx, int E,
                                                 const int* __restrict__ flag,
                                                 const float* __restrict__ dinv,
                                                 int* __restrict__ cursor,
                                                 int2* __restrict__ rec) {
    int e = blockIdx.x * 256 + threadIdx.x;
    if (e >= E) return;
    int s, d;
    if (*flag) {
        s = (int)((const long long*)eidx)[e];
        d = (int)((const long long*)eidx)[E + e];
    } else {
        s = ((const int*)eidx)[e];
        d = ((const int*)eidx)[E + e];
    }
    float nrm = dinv[s] * dinv[d];
    int pos = atomicAdd(&cursor[d], 1);
    rec[pos] = make_int2(s, __float_as_int(nrm));
}

// Y[n,128] = act(X)[n,128] @ W[128,128].
// act = relu(x*scale + shift) if scale != nullptr (folded BN+ReLU).
// Output: bf16 to Yb (if non-null) and/or f32 to Yf (if non-null).
__global__ __launch_bounds__(256) void k_gemm(const float* __restrict__ X,
                                              const float* __restrict__ W,
                                              int n,
                                              const float* __restrict__ scale,
                                              const float* __restrict__ shift,
                                              unsigned short* __restrict__ Yb,
                                              float* __restrict__ Yf) {
    __shared__ float Ws[128 * 128];  // 64 KiB
    __shared__ float Xs[32 * 128];   // 16 KiB
    const int tid = threadIdx.x;
    for (int i = tid; i < 128 * 32; i += 256)
        ((float4*)Ws)[i] = ((const float4*)W)[i];
    const int row0 = blockIdx.x * 32;
    if (scale) {
        for (int i = tid; i < 32 * 32; i += 256) {
            int r = i >> 5, c = i & 31;
            int gr = row0 + r;
            float4 v = (gr < n) ? ((const float4*)X)[(size_t)gr * 32 + c]
                                : float4{0.f, 0.f, 0.f, 0.f};
            float4 sc = ((const float4*)scale)[c];
            float4 sh = ((const float4*)shift)[c];
            v.x = fmaxf(fmaf(v.x, sc.x, sh.x), 0.f);
            v.y = fmaxf(fmaf(v.y, sc.y, sh.y), 0.f);
            v.z = fmaxf(fmaf(v.z, sc.z, sh.z), 0.f);
            v.w = fmaxf(fmaf(v.w, sc.w, sh.w), 0.f);
            ((float4*)Xs)[i] = v;
        }
    } else {
        for (int i = tid; i < 32 * 32; i += 256) {
            int r = i >> 5, c = i & 31;
            int gr = row0 + r;
            float4 v = (gr < n) ? ((const float4*)X)[(size_t)gr * 32 + c]
                                : float4{0.f, 0.f, 0.f, 0.f};
            ((float4*)Xs)[i] = v;
        }
    }
    __syncthreads();
    const int c4 = (tid & 31) * 4;
    const int rb = tid >> 5;  // 0..7; thread owns rows rb+8j, j=0..3
    float4 acc[4];
#pragma unroll
    for (int j = 0; j < 4; ++j) acc[j] = float4{0.f, 0.f, 0.f, 0.f};
    for (int k = 0; k < 128; ++k) {
        float4 w = *(const float4*)&Ws[k * 128 + c4];
#pragma unroll
        for (int j = 0; j < 4; ++j) {
            float xv = Xs[(rb + 8 * j) * 128 + k];
            acc[j].x = fmaf(xv, w.x, acc[j].x);
            acc[j].y = fmaf(xv, w.y, acc[j].y);
            acc[j].z = fmaf(xv, w.z, acc[j].z);
            acc[j].w = fmaf(xv, w.w, acc[j].w);
        }
    }
#pragma unroll
    for (int j = 0; j < 4; ++j) {
        int r = row0 + rb + 8 * j;
        if (r < n) {
            if (Yb) {
                uint2 pk;
                pk.x = rne_bf16(acc[j].x) | (rne_bf16(acc[j].y) << 16);
                pk.y = rne_bf16(acc[j].z) | (rne_bf16(acc[j].w) << 16);
                *(uint2*)&Yb[(size_t)r * 128 + c4] = pk;
            }
            if (Yf) *(float4*)&Yf[(size_t)r * 128 + c4] = acc[j];
        }
    }
}

// One wave per dst row, bf16 H rows (256 B gather/row):
// B[d] = H[d]*dinv[d]^2 + bias + sum_{e} H[src_e]*norm_e
__global__ __launch_bounds__(256) void k_agg(const int2* __restrict__ rec,
                                             const int* __restrict__ row_ptr,
                                             const unsigned* __restrict__ Hb,  // n x 64 uints
                                             const float* __restrict__ dinv,
                                             const float* __restrict__ bias,
                                             float* __restrict__ B, int n) {
    const int d = blockIdx.x * 4 + (threadIdx.x >> 6);
    if (d >= n) return;
    const int lane = threadIdx.x & 63;
    float s = dinv[d];
    s *= s;
    unsigned hu = Hb[(size_t)d * 64 + lane];
    float2 bb = ((const float2*)bias)[lane];
    float accx = fmaf(__uint_as_float(hu << 16), s, bb.x);
    float accy = fmaf(__uint_as_float(hu & 0xffff0000u), s, bb.y);
    int e = __builtin_amdgcn_readfirstlane(row_ptr[d]);
    const int end = __builtin_amdgcn_readfirstlane(row_ptr[d + 1]);
    if ((e & 1) && e < end) {  // align to 16B for int4 loads
        int2 r0 = rec[e];
        unsigned u0 = Hb[(size_t)r0.x * 64 + lane];
        float n0 = __int_as_float(r0.y);
        accx = fmaf(__uint_as_float(u0 << 16), n0, accx);
        accy = fmaf(__uint_as_float(u0 & 0xffff0000u), n0, accy);
        ++e;
    }
    for (; e + 3 < end; e += 4) {
        int4 ra = *(const int4*)&rec[e];
        int4 rb = *(const int4*)&rec[e + 2];
        unsigned u0 = Hb[(size_t)ra.x * 64 + lane];
        unsigned u1 = Hb[(size_t)ra.z * 64 + lane];
        unsigned u2 = Hb[(size_t)rb.x * 64 + lane];
        unsigned u3 = Hb[(size_t)rb.z * 64 + lane];
        float n0 = __int_as_float(ra.y), n1 = __int_as_float(ra.w);
        float n2 = __int_as_float(rb.y), n3 = __int_as_float(rb.w);
        accx = fmaf(__uint_as_float(u0 << 16), n0, accx);
        accy = fmaf(__uint_as_float(u0 & 0xffff0000u), n0, accy);
        accx = fmaf(__uint_as_float(u1 << 16), n1, accx);
        accy = fmaf(__uint_as_float(u1 & 0xffff0000u), n1, accy);
        accx = fmaf(__uint_as_float(u2 << 16), n2, accx);
        accy = fmaf(__uint_as_float(u2 & 0xffff0000u), n2, accy);
        accx = fmaf(__uint_as_float(u3 << 16), n3, accx);
        accy = fmaf(__uint_as_float(u3 & 0xffff0000u), n3, accy);
    }
    for (; e < end; ++e) {
        int2 r0 = rec[e];
        unsigned u0 = Hb[(size_t)r0.x * 64 + lane];
        float n0 = __int_as_float(r0.y);
        accx = fmaf(__uint_as_float(u0 << 16), n0, accx);
        accy = fmaf(__uint_as_float(u0 & 0xffff0000u), n0, accy);
    }
    ((float2*)(B + (size_t)d * 128))[lane] = make_float2(accx, accy);
}

// Fold BN affine: scale[c] = gamma*rsqrt(var+eps), shift[c] = beta - mean*scale
__global__ __launch_bounds__(128) void k_bnfold(const float* __restrict__ stats,
                                                const float* __restrict__ gamma,
                                                const float* __restrict__ beta,
                                                float invn,
                                                float* __restrict__ scale,
                                                float* __restrict__ shift) {
    int c = threadIdx.x;
    float m = stats[c] * invn;
    float var = fmaf(-m, m, stats[128 + c] * invn);
    float sc = rsqrtf(var + BN_EPS) * gamma[c];
    scale[c] = sc;
    shift[c] = fmaf(-m, sc, beta[c]);
}

// ---- fallback (atomic) path kernels ----
__global__ __launch_bounds__(256) void k_selfloop(const float* __restrict__ H,
                                                  const float* __restrict__ dinv,
                                                  const float* __restrict__ bias,
                                                  float* __restrict__ B, int n) {
    int idx = blockIdx.x * 256 + threadIdx.x;
    int total = n * 32;
    if (idx >= total) return;
    int r = idx >> 5, c = idx & 31;
    float s = dinv[r];
    s *= s;
    float4 h = ((const float4*)H)[idx];
    float4 bb = ((const float4*)bias)[c];
    float4 o{fmaf(h.x, s, bb.x), fmaf(h.y, s, bb.y),
             fmaf(h.z, s, bb.z), fmaf(h.w, s, bb.w)};
    ((float4*)B)[idx] = o;
}

__global__ __launch_bounds__(256) void k_edge(const void* __restrict__ eidx, int E,
                                              const int* __restrict__ flag,
                                              const float* __restrict__ dinv,
                                              const float* __restrict__ H,
                                              float* __restrict__ B) {
    int e = blockIdx.x * 8 + (threadIdx.x >> 5);
    if (e >= E) return;
    int lane = threadIdx.x & 31;
    int s, d;
    if (*flag) {
        s = (int)((const long long*)eidx)[e];
        d = (int)((const long long*)eidx)[E + e];
    } else {
        s = ((const int*)eidx)[e];
        d = ((const int*)eidx)[E + e];
    }
    float nrm = dinv[s] * dinv[d];
    float4 h = ((const float4*)(H + (size_t)s * 128))[lane];
    float* out = B + (size_t)d * 128 + lane * 4;
    atomicAdd(out + 0, h.x * nrm);
    atomicAdd(out + 1, h.y * nrm);
    atomicAdd(out + 2, h.z * nrm);
    atomicAdd(out + 3, h.w * nrm);
}

// Column sums / sumsq into stats[0:128]=sum, stats[128:256]=sumsq (pre-zeroed).
__global__ __launch_bounds__(256) void k_bnstats(const float* __restrict__ B, int n,
                                                 float* __restrict__ stats) {
    __shared__ float rs[256], rss[256];
    int col = threadIdx.x & 127;
    int rg = threadIdx.x >> 7;
    float s = 0.f, ss = 0.f;
    for (int r = blockIdx.x * 2 + rg; r < n; r += gridDim.x * 2) {
        float v = B[(size_t)r * 128 + col];
        s += v;
        ss = fmaf(v, v, ss);
    }
    rs[threadIdx.x] = s;
    rss[threadIdx.x] = ss;
    __syncthreads();
    if (threadIdx.x < 128) {
        atomicAdd(&stats[col], rs[threadIdx.x] + rs[threadIdx.x + 128]);
        atomicAdd(&stats[128 + col], rss[threadIdx.x] + rss[threadIdx.x + 128]);
    }
}

__global__ __launch_bounds__(256) void k_bnapply(const float* __restrict__ Bin,
                                                 float* __restrict__ out,
                                                 const float* __restrict__ stats,
                                                 const float* __restrict__ gamma,
                                                 const float* __restrict__ beta,
                                                 int n, float invn) {
    int idx = blockIdx.x * 256 + threadIdx.x;
    int total = n * 32;
    if (idx >= total) return;
    int c4 = (idx & 31) * 4;
    float4 x = ((const float4*)Bin)[idx];
    float4 o;
#pragma unroll
    for (int j = 0; j < 4; ++j) {
        int c = c4 + j;
        float m = stats[c] * invn;
        float var = fmaf(-m, m, stats[128 + c] * invn);
        float sc = rsqrtf(var + BN_EPS) * gamma[c];
        float sh = fmaf(-m, sc, beta[c]);
        float v = fmaf((&x.x)[j], sc, sh);
        (&o.x)[j] = fmaxf(v, 0.f);
    }
    ((float4*)out)[idx] = o;
}

static inline char* align256(char* p) {
    return (char*)(((uintptr_t)p + 255) & ~(uintptr_t)255);
}

extern "C" void kernel_launch(void* const* d_in, const int* in_sizes, int n_in,
                              void* d_out, int out_size, void* d_ws, size_t ws_size,
                              hipStream_t stream) {
    const float* x   = (const float*)d_in[0];
    const void*  ei  = d_in[1];
    const float* W1  = (const float*)d_in[2];
    const float* b1  = (const float*)d_in[3];
    const float* g1  = (const float*)d_in[4];
    const float* be1 = (const float*)d_in[5];
    const float* W2  = (const float*)d_in[6];
    const float* b2  = (const float*)d_in[7];
    const float* g2  = (const float*)d_in[8];
    const float* be2 = (const float*)d_in[9];

    const int n = in_sizes[0] / 128;
    const int E = in_sizes[1] / 2;
    const float invn = 1.0f / (float)n;
    const int nb_scan = (n + SCAN_TILE - 1) / SCAN_TILE;

    char* p = (char*)d_ws;
    float* A = (float*)p;            p += (size_t)n * 128 * 4;   // f32 H (fallback only)
    float* B = (float*)p;            p += (size_t)n * 128 * 4;
    unsigned short* Ab = (unsigned short*)p; p += (size_t)n * 128 * 2;  // bf16 H
    p = align256(p);
    int2*  rec = (int2*)p;           p += (size_t)E * 8;
    int*   row_ptr = (int*)p;        p += (size_t)(n + 1) * 4;
    p = align256(p);
    int*   cursor = (int*)p;         p += (size_t)n * 4;
    p = align256(p);
    int*   deg = (int*)p;            p += (size_t)n * 4;
    p = align256(p);
    float* dinv = (float*)p;         p += (size_t)n * 4;
    p = align256(p);
    float* stats = (float*)p;        p += 256 * 4;
    float* scale = (float*)p;        p += 128 * 4;
    float* shift = (float*)p;        p += 128 * 4;
    int*   flag = (int*)p;           p += 16;
    int*   partials = (int*)p;       p += (size_t)nb_scan * 4;
    const size_t needed = (size_t)(p - (char*)d_ws);
    const bool csr_ok = needed <= ws_size;
    float* out = (float*)d_out;

    const int nb_n    = (n + 255) / 256;
    const int nb_e    = (E + 255) / 256;
    const int nb_el   = (n * 32 + 255) / 256;
    const int nb_gm   = (n + 31) / 32;
    const int nb_edge = (E + 7) / 8;
    const int nb_agg  = (n + 3) / 4;

    k_detect_i64<<<1, 256, 0, stream>>>((const unsigned*)ei, flag);
    k_init_deg<<<nb_n, 256, 0, stream>>>(deg, n);
    k_count_deg<<<nb_e, 256, 0, stream>>>(ei, E, flag, deg);

    if (csr_ok) {
        k_scan1<<<nb_scan, 256, 0, stream>>>(deg, n, partials, dinv);
        k_scan2<<<1, 64, 0, stream>>>(partials, nb_scan, row_ptr + n);
        k_scan3<<<nb_scan, 256, 0, stream>>>(deg, n, partials, row_ptr, cursor);
        k_scatter<<<nb_e, 256, 0, stream>>>(ei, E, flag, dinv, cursor, rec);

        // ---- layer 1 ----
        k_gemm<<<nb_gm, 256, 0, stream>>>(x, W1, n, nullptr, nullptr, Ab, nullptr);
        k_agg<<<nb_agg, 256, 0, stream>>>(rec, row_ptr, (const unsigned*)Ab, dinv, b1, B, n);
        hipMemsetAsync(stats, 0, 256 * sizeof(float), stream);
        k_bnstats<<<256, 256, 0, stream>>>(B, n, stats);
        k_bnfold<<<1, 128, 0, stream>>>(stats, g1, be1, invn, scale, shift);

        // ---- layer 2 (BN1+ReLU folded into GEMM staging) ----
        k_gemm<<<nb_gm, 256, 0, stream>>>(B, W2, n, scale, shift, Ab, nullptr);
        k_agg<<<nb_agg, 256, 0, stream>>>(rec, row_ptr, (const unsigned*)Ab, dinv, b2, B, n);
        hipMemsetAsync(stats, 0, 256 * sizeof(float), stream);
        k_bnstats<<<256, 256, 0, stream>>>(B, n, stats);
        k_bnapply<<<nb_el, 256, 0, stream>>>(B, out, stats, g2, be2, n, invn);
    } else {
        // fallback: atomic scatter path (f32 H)
        k_dinv<<<nb_n, 256, 0, stream>>>(deg, dinv, n);
        k_gemm<<<nb_gm, 256, 0, stream>>>(x, W1, n, nullptr, nullptr, nullptr, A);
        k_selfloop<<<nb_el, 256, 0, stream>>>(A, dinv, b1, B, n);
        k_edge<<<nb_edge, 256, 0, stream>>>(ei, E, flag, dinv, A, B);
        hipMemsetAsync(stats, 0, 256 * sizeof(float), stream);
        k_bnstats<<<256, 256, 0, stream>>>(B, n, stats);
        k_bnapply<<<nb_el, 256, 0, stream>>>(B, B, stats, g1, be1, n, invn);

        k_gemm<<<nb_gm, 256, 0, stream>>>(B, W2, n, nullptr, nullptr, nullptr, A);
        k_selfloop<<<nb_el, 256, 0, stream>>>(A, dinv, b2, B, n);
        k_edge<<<nb_edge, 256, 0, stream>>>(ei, E, flag, dinv, A, B);
        hipMemsetAsync(stats, 0, 256 * sizeof(float), stream);
        k_bnstats<<<256, 256, 0, stream>>>(B, n, stats);
        k_bnapply<<<nb_el, 256, 0, stream>>>(B, out, stats, g2, be2, n, invn);
    }
}

// Round 6
// 306.535 us; speedup vs baseline: 9.5730x; 1.0391x over previous
//
#include <hip/hip_runtime.h>

static constexpr float BN_EPS = 1e-5f;
#define ELLW 64

__device__ __forceinline__ unsigned rne_bf16(float f) {
    unsigned u = __float_as_uint(f);
    u += 0x7fffu + ((u >> 16) & 1u);
    return u >> 16;
}
__device__ __forceinline__ float bflo(unsigned u) { return __uint_as_float(u << 16); }
__device__ __forceinline__ float bfhi(unsigned u) { return __uint_as_float(u & 0xffff0000u); }

// Detect whether edge_index is int64 (high words all zero) or int32.
__global__ __launch_bounds__(256) void k_detect_i64(const unsigned* __restrict__ ei,
                                                    int* __restrict__ flag) {
    if (blockIdx.x == 0 && threadIdx.x == 0) {
        int allz = 1;
        for (int i = 0; i < 256; ++i) {
            if (ei[2 * i + 1] != 0u) { allz = 0; break; }
        }
        *flag = allz;
    }
}

// One pass: count degree AND bin edges into fixed-width ELL rows.
// deg[d] counts incoming edges (self-loop handled as +1 downstream).
__global__ __launch_bounds__(256) void k_ell(const void* __restrict__ eidx, int E,
                                             const int* __restrict__ flag,
                                             int* __restrict__ deg,
                                             int* __restrict__ rec,
                                             int2* __restrict__ ovf,
                                             int* __restrict__ ovf_cnt, int ovf_cap) {
    int e = blockIdx.x * 256 + threadIdx.x;
    if (e >= E) return;
    int s, d;
    if (*flag) {
        s = (int)((const long long*)eidx)[e];
        d = (int)((const long long*)eidx)[E + e];
    } else {
        s = ((const int*)eidx)[e];
        d = ((const int*)eidx)[E + e];
    }
    int pos = atomicAdd(&deg[d], 1);
    if (pos < ELLW) {
        rec[(size_t)d * ELLW + pos] = s;
    } else {
        int o = atomicAdd(ovf_cnt, 1);
        if (o < ovf_cap) ovf[o] = make_int2(s, d);
    }
}

// Y[n,128] = act(X)[n,128] @ W[128,128].
// act = relu(x*scale + shift) if scale != nullptr (folded BN+ReLU).
// Output: bf16 to Yb (if non-null) and/or f32 to Yf (if non-null).
__global__ __launch_bounds__(256) void k_gemm(const float* __restrict__ X,
                                              const float* __restrict__ W,
                                              int n,
                                              const float* __restrict__ scale,
                                              const float* __restrict__ shift,
                                              unsigned short* __restrict__ Yb,
                                              float* __restrict__ Yf) {
    __shared__ float Ws[128 * 128];  // 64 KiB
    __shared__ float Xs[32 * 128];   // 16 KiB
    const int tid = threadIdx.x;
    for (int i = tid; i < 128 * 32; i += 256)
        ((float4*)Ws)[i] = ((const float4*)W)[i];
    const int row0 = blockIdx.x * 32;
    if (scale) {
        for (int i = tid; i < 32 * 32; i += 256) {
            int r = i >> 5, c = i & 31;
            int gr = row0 + r;
            float4 v = (gr < n) ? ((const float4*)X)[(size_t)gr * 32 + c]
                                : float4{0.f, 0.f, 0.f, 0.f};
            float4 sc = ((const float4*)scale)[c];
            float4 sh = ((const float4*)shift)[c];
            v.x = fmaxf(fmaf(v.x, sc.x, sh.x), 0.f);
            v.y = fmaxf(fmaf(v.y, sc.y, sh.y), 0.f);
            v.z = fmaxf(fmaf(v.z, sc.z, sh.z), 0.f);
            v.w = fmaxf(fmaf(v.w, sc.w, sh.w), 0.f);
            ((float4*)Xs)[i] = v;
        }
    } else {
        for (int i = tid; i < 32 * 32; i += 256) {
            int r = i >> 5, c = i & 31;
            int gr = row0 + r;
            float4 v = (gr < n) ? ((const float4*)X)[(size_t)gr * 32 + c]
                                : float4{0.f, 0.f, 0.f, 0.f};
            ((float4*)Xs)[i] = v;
        }
    }
    __syncthreads();
    const int c4 = (tid & 31) * 4;
    const int rb = tid >> 5;
    float4 acc[4];
#pragma unroll
    for (int j = 0; j < 4; ++j) acc[j] = float4{0.f, 0.f, 0.f, 0.f};
    for (int k = 0; k < 128; ++k) {
        float4 w = *(const float4*)&Ws[k * 128 + c4];
#pragma unroll
        for (int j = 0; j < 4; ++j) {
            float xv = Xs[(rb + 8 * j) * 128 + k];
            acc[j].x = fmaf(xv, w.x, acc[j].x);
            acc[j].y = fmaf(xv, w.y, acc[j].y);
            acc[j].z = fmaf(xv, w.z, acc[j].z);
            acc[j].w = fmaf(xv, w.w, acc[j].w);
        }
    }
#pragma unroll
    for (int j = 0; j < 4; ++j) {
        int r = row0 + rb + 8 * j;
        if (r < n) {
            if (Yb) {
                uint2 pk;
                pk.x = rne_bf16(acc[j].x) | (rne_bf16(acc[j].y) << 16);
                pk.y = rne_bf16(acc[j].z) | (rne_bf16(acc[j].w) << 16);
                *(uint2*)&Yb[(size_t)r * 128 + c4] = pk;
            }
            if (Yf) *(float4*)&Yf[(size_t)r * 128 + c4] = acc[j];
        }
    }
}

// One wave per dst row, ELL records (4B src), norms from deg (L2-resident):
// B[d] = H[d]/(cnt+1) + bias + sum_e H[src_e] * rsqrt(deg_s+1)*rsqrt(cnt+1)
__global__ __launch_bounds__(256) void k_agg(const int* __restrict__ rec,
                                             const int* __restrict__ deg,
                                             const unsigned* __restrict__ Hb,
                                             const float* __restrict__ bias,
                                             float* __restrict__ B, int n) {
    const int d = blockIdx.x * 4 + (threadIdx.x >> 6);
    if (d >= n) return;
    const int lane = threadIdx.x & 63;
    const int cnt = __builtin_amdgcn_readfirstlane(deg[d]);
    const int cl = cnt < ELLW ? cnt : ELLW;
    const float dinv_d = rsqrtf((float)(cnt + 1));
    const float selfn = dinv_d * dinv_d;
    unsigned hu = Hb[(size_t)d * 64 + lane];
    float2 bb = ((const float2*)bias)[lane];
    float accx = fmaf(bflo(hu), selfn, bb.x);
    float accy = fmaf(bfhi(hu), selfn, bb.y);
    const int* row = rec + (size_t)d * ELLW;
    int e = 0;
    for (; e + 3 < cl; e += 4) {
        int4 r = *(const int4*)&row[e];
        float n0 = rsqrtf((float)(deg[r.x] + 1)) * dinv_d;
        float n1 = rsqrtf((float)(deg[r.y] + 1)) * dinv_d;
        float n2 = rsqrtf((float)(deg[r.z] + 1)) * dinv_d;
        float n3 = rsqrtf((float)(deg[r.w] + 1)) * dinv_d;
        unsigned u0 = Hb[(size_t)r.x * 64 + lane];
        unsigned u1 = Hb[(size_t)r.y * 64 + lane];
        unsigned u2 = Hb[(size_t)r.z * 64 + lane];
        unsigned u3 = Hb[(size_t)r.w * 64 + lane];
        accx = fmaf(bflo(u0), n0, accx); accy = fmaf(bfhi(u0), n0, accy);
        accx = fmaf(bflo(u1), n1, accx); accy = fmaf(bfhi(u1), n1, accy);
        accx = fmaf(bflo(u2), n2, accx); accy = fmaf(bfhi(u2), n2, accy);
        accx = fmaf(bflo(u3), n3, accx); accy = fmaf(bfhi(u3), n3, accy);
    }
    for (; e < cl; ++e) {
        int r = row[e];
        float n0 = rsqrtf((float)(deg[r] + 1)) * dinv_d;
        unsigned u0 = Hb[(size_t)r * 64 + lane];
        accx = fmaf(bflo(u0), n0, accx); accy = fmaf(bfhi(u0), n0, accy);
    }
    ((float2*)(B + (size_t)d * 128))[lane] = make_float2(accx, accy);
}

// Replay overflow edges (normally zero) with f32 atomics.
__global__ __launch_bounds__(256) void k_ovf(const int2* __restrict__ ovf,
                                             const int* __restrict__ ovf_cnt,
                                             const int* __restrict__ deg,
                                             const unsigned* __restrict__ Hb,
                                             float* __restrict__ B, int ovf_cap) {
    int m = *ovf_cnt;
    if (m > ovf_cap) m = ovf_cap;
    const int lane = threadIdx.x & 63;
    for (int i = blockIdx.x * 4 + (threadIdx.x >> 6); i < m; i += gridDim.x * 4) {
        int2 sd = ovf[i];
        float nrm = rsqrtf((float)(deg[sd.x] + 1)) * rsqrtf((float)(deg[sd.y] + 1));
        unsigned u = Hb[(size_t)sd.x * 64 + lane];
        atomicAdd(&B[(size_t)sd.y * 128 + 2 * lane], bflo(u) * nrm);
        atomicAdd(&B[(size_t)sd.y * 128 + 2 * lane + 1], bfhi(u) * nrm);
    }
}

// Per-block column partials: partials[blk*256 + 0:128]=sum, [128:256]=sumsq.
__global__ __launch_bounds__(256) void k_bnstats(const float* __restrict__ B, int n,
                                                 float* __restrict__ partials) {
    __shared__ float rs[256], rss[256];
    int col = threadIdx.x & 127;
    int rg = threadIdx.x >> 7;
    float s = 0.f, ss = 0.f;
    for (int r = blockIdx.x * 2 + rg; r < n; r += gridDim.x * 2) {
        float v = B[(size_t)r * 128 + col];
        s += v;
        ss = fmaf(v, v, ss);
    }
    rs[threadIdx.x] = s;
    rss[threadIdx.x] = ss;
    __syncthreads();
    if (threadIdx.x < 128) {
        partials[blockIdx.x * 256 + threadIdx.x] = rs[threadIdx.x] + rs[threadIdx.x + 128];
        partials[blockIdx.x * 256 + 128 + threadIdx.x] = rss[threadIdx.x] + rss[threadIdx.x + 128];
    }
}

// Reduce 256 partial blocks -> folded BN affine (scale, shift).
__global__ __launch_bounds__(128) void k_bnfold(const float* __restrict__ partials,
                                                const float* __restrict__ gamma,
                                                const float* __restrict__ beta,
                                                float invn,
                                                float* __restrict__ scale,
                                                float* __restrict__ shift) {
    int c = threadIdx.x;
    float s = 0.f, ss = 0.f;
    for (int b = 0; b < 256; ++b) {
        s += partials[b * 256 + c];
        ss += partials[b * 256 + 128 + c];
    }
    float m = s * invn;
    float var = fmaf(-m, m, ss * invn);
    float sc = rsqrtf(var + BN_EPS) * gamma[c];
    scale[c] = sc;
    shift[c] = fmaf(-m, sc, beta[c]);
}

// out = relu(x*scale + shift)
__global__ __launch_bounds__(256) void k_bnapply(const float* __restrict__ Bin,
                                                 float* __restrict__ out,
                                                 const float* __restrict__ scale,
                                                 const float* __restrict__ shift,
                                                 int n) {
    int idx = blockIdx.x * 256 + threadIdx.x;
    if (idx >= n * 32) return;
    int c4 = idx & 31;
    float4 x = ((const float4*)Bin)[idx];
    float4 sc = ((const float4*)scale)[c4];
    float4 sh = ((const float4*)shift)[c4];
    float4 o;
    o.x = fmaxf(fmaf(x.x, sc.x, sh.x), 0.f);
    o.y = fmaxf(fmaf(x.y, sc.y, sh.y), 0.f);
    o.z = fmaxf(fmaf(x.z, sc.z, sh.z), 0.f);
    o.w = fmaxf(fmaf(x.w, sc.w, sh.w), 0.f);
    ((float4*)out)[idx] = o;
}

// ---- fallback (atomic) path kernels ----
__global__ __launch_bounds__(256) void k_init_deg(int* __restrict__ deg, int n) {
    int i = blockIdx.x * 256 + threadIdx.x;
    if (i < n) deg[i] = 1;
}

__global__ __launch_bounds__(256) void k_count_deg(const void* __restrict__ eidx, int E,
                                                   const int* __restrict__ flag,
                                                   int* __restrict__ deg) {
    int e = blockIdx.x * 256 + threadIdx.x;
    if (e >= E) return;
    int d;
    if (*flag) d = (int)((const long long*)eidx)[E + e];
    else       d = ((const int*)eidx)[E + e];
    atomicAdd(&deg[d], 1);
}

__global__ __launch_bounds__(256) void k_dinv(const int* __restrict__ deg,
                                              float* __restrict__ dinv, int n) {
    int i = blockIdx.x * 256 + threadIdx.x;
    if (i < n) dinv[i] = rsqrtf((float)deg[i]);
}

__global__ __launch_bounds__(256) void k_selfloop(const float* __restrict__ H,
                                                  const float* __restrict__ dinv,
                                                  const float* __restrict__ bias,
                                                  float* __restrict__ B, int n) {
    int idx = blockIdx.x * 256 + threadIdx.x;
    if (idx >= n * 32) return;
    int r = idx >> 5, c = idx & 31;
    float s = dinv[r];
    s *= s;
    float4 h = ((const float4*)H)[idx];
    float4 bb = ((const float4*)bias)[c];
    float4 o{fmaf(h.x, s, bb.x), fmaf(h.y, s, bb.y),
             fmaf(h.z, s, bb.z), fmaf(h.w, s, bb.w)};
    ((float4*)B)[idx] = o;
}

__global__ __launch_bounds__(256) void k_edge(const void* __restrict__ eidx, int E,
                                              const int* __restrict__ flag,
                                              const float* __restrict__ dinv,
                                              const float* __restrict__ H,
                                              float* __restrict__ B) {
    int e = blockIdx.x * 8 + (threadIdx.x >> 5);
    if (e >= E) return;
    int lane = threadIdx.x & 31;
    int s, d;
    if (*flag) {
        s = (int)((const long long*)eidx)[e];
        d = (int)((const long long*)eidx)[E + e];
    } else {
        s = ((const int*)eidx)[e];
        d = ((const int*)eidx)[E + e];
    }
    float nrm = dinv[s] * dinv[d];
    float4 h = ((const float4*)(H + (size_t)s * 128))[lane];
    float* out = B + (size_t)d * 128 + lane * 4;
    atomicAdd(out + 0, h.x * nrm);
    atomicAdd(out + 1, h.y * nrm);
    atomicAdd(out + 2, h.z * nrm);
    atomicAdd(out + 3, h.w * nrm);
}

static inline char* align256(char* p) {
    return (char*)(((uintptr_t)p + 255) & ~(uintptr_t)255);
}

extern "C" void kernel_launch(void* const* d_in, const int* in_sizes, int n_in,
                              void* d_out, int out_size, void* d_ws, size_t ws_size,
                              hipStream_t stream) {
    const float* x   = (const float*)d_in[0];
    const void*  ei  = d_in[1];
    const float* W1  = (const float*)d_in[2];
    const float* b1  = (const float*)d_in[3];
    const float* g1  = (const float*)d_in[4];
    const float* be1 = (const float*)d_in[5];
    const float* W2  = (const float*)d_in[6];
    const float* b2  = (const float*)d_in[7];
    const float* g2  = (const float*)d_in[8];
    const float* be2 = (const float*)d_in[9];

    const int n = in_sizes[0] / 128;
    const int E = in_sizes[1] / 2;
    const float invn = 1.0f / (float)n;
    float* out = (float*)d_out;

    const int nb_n   = (n + 255) / 256;
    const int nb_e   = (E + 255) / 256;
    const int nb_el  = (n * 32 + 255) / 256;
    const int nb_gm  = (n + 31) / 32;
    const int nb_agg = (n + 3) / 4;
    const int nb_edge = (E + 7) / 8;

    // ---- main (ELL) layout ----
    char* p = (char*)d_ws;
    float* B = (float*)p;                      p += (size_t)n * 128 * 4;
    unsigned short* Ab = (unsigned short*)p;   p += (size_t)n * 128 * 2;
    p = align256(p);
    int* rec = (int*)p;                        p += (size_t)n * ELLW * 4;
    int2* ovf = (int2*)p;                      p += (size_t)E * 8;
    int* deg = (int*)p;                        p += (size_t)n * 4;
    int* ovf_cnt = (int*)p;                    p += 4;   // contiguous with deg: one memset
    p = align256(p);
    float* partials = (float*)p;               p += 256 * 256 * 4;
    float* scale = (float*)p;                  p += 128 * 4;
    float* shift = (float*)p;                  p += 128 * 4;
    int* flag = (int*)p;                       p += 16;
    const bool ell_ok = (size_t)(p - (char*)d_ws) <= ws_size;

    if (ell_ok) {
        k_detect_i64<<<1, 256, 0, stream>>>((const unsigned*)ei, flag);
        hipMemsetAsync(deg, 0, (size_t)n * 4 + 4, stream);  // deg + ovf_cnt
        k_ell<<<nb_e, 256, 0, stream>>>(ei, E, flag, deg, rec, ovf, ovf_cnt, E);

        // ---- layer 1 ----
        k_gemm<<<nb_gm, 256, 0, stream>>>(x, W1, n, nullptr, nullptr, Ab, nullptr);
        k_agg<<<nb_agg, 256, 0, stream>>>(rec, deg, (const unsigned*)Ab, b1, B, n);
        k_ovf<<<64, 256, 0, stream>>>(ovf, ovf_cnt, deg, (const unsigned*)Ab, B, E);
        k_bnstats<<<256, 256, 0, stream>>>(B, n, partials);
        k_bnfold<<<1, 128, 0, stream>>>(partials, g1, be1, invn, scale, shift);

        // ---- layer 2 (BN1+ReLU folded into GEMM staging) ----
        k_gemm<<<nb_gm, 256, 0, stream>>>(B, W2, n, scale, shift, Ab, nullptr);
        k_agg<<<nb_agg, 256, 0, stream>>>(rec, deg, (const unsigned*)Ab, b2, B, n);
        k_ovf<<<64, 256, 0, stream>>>(ovf, ovf_cnt, deg, (const unsigned*)Ab, B, E);
        k_bnstats<<<256, 256, 0, stream>>>(B, n, partials);
        k_bnfold<<<1, 128, 0, stream>>>(partials, g2, be2, invn, scale, shift);
        k_bnapply<<<nb_el, 256, 0, stream>>>(B, out, scale, shift, n);
    } else {
        // ---- fallback: atomic scatter path (f32 H) ----
        char* q = (char*)d_ws;
        float* A = (float*)q;        q += (size_t)n * 128 * 4;
        float* Bf = (float*)q;       q += (size_t)n * 128 * 4;
        int* degf = (int*)q;         q += (size_t)n * 4;
        float* dinv = (float*)q;     q += (size_t)n * 4;
        q = align256(q);
        float* part = (float*)q;     q += 256 * 256 * 4;
        float* sc = (float*)q;       q += 128 * 4;
        float* sh = (float*)q;       q += 128 * 4;
        int* flg = (int*)q;          q += 16;

        k_detect_i64<<<1, 256, 0, stream>>>((const unsigned*)ei, flg);
        k_init_deg<<<nb_n, 256, 0, stream>>>(degf, n);
        k_count_deg<<<nb_e, 256, 0, stream>>>(ei, E, flg, degf);
        k_dinv<<<nb_n, 256, 0, stream>>>(degf, dinv, n);

        k_gemm<<<nb_gm, 256, 0, stream>>>(x, W1, n, nullptr, nullptr, nullptr, A);
        k_selfloop<<<nb_el, 256, 0, stream>>>(A, dinv, b1, Bf, n);
        k_edge<<<nb_edge, 256, 0, stream>>>(ei, E, flg, dinv, A, Bf);
        k_bnstats<<<256, 256, 0, stream>>>(Bf, n, part);
        k_bnfold<<<1, 128, 0, stream>>>(part, g1, be1, invn, sc, sh);
        k_bnapply<<<nb_el, 256, 0, stream>>>(Bf, Bf, sc, sh, n);

        k_gemm<<<nb_gm, 256, 0, stream>>>(Bf, W2, n, nullptr, nullptr, nullptr, A);
        k_selfloop<<<nb_el, 256, 0, stream>>>(A, dinv, b2, Bf, n);
        k_edge<<<nb_edge, 256, 0, stream>>>(ei, E, flg, dinv, A, Bf);
        k_bnstats<<<256, 256, 0, stream>>>(Bf, n, part);
        k_bnfold<<<1, 128, 0, stream>>>(part, g2, be2, invn, sc, sh);
        k_bnapply<<<nb_el, 256, 0, stream>>>(Bf, out, sc, sh, n);
    }
}